// Round 4
// baseline (331.291 us; speedup 1.0000x reference)
//
#include <hip/hip_runtime.h>
#include <hip/hip_bf16.h>

typedef unsigned int u32;
typedef unsigned short u16;

__device__ __forceinline__ float lrelu(float v) {
    return v > 0.f ? v : 0.2f * v;
}

// ---------------- GEMM1: h = x @ W1  [n,128]x[128,32], + row dots ----------
__global__ __launch_bounds__(256) void gemm1_kernel(
    const float* __restrict__ x, const float* __restrict__ W,
    const float* __restrict__ a_src, const float* __restrict__ a_dst,
    float* __restrict__ h, float* __restrict__ as_, float* __restrict__ ad_,
    int n)
{
    __shared__ float xs[64][132];
    __shared__ float Wl[128][32];
    __shared__ float asv[32], adv[32];
    int t = threadIdx.x;
    int rb = blockIdx.x * 64;

    for (int i = t; i < 4096; i += 256) Wl[i >> 5][i & 31] = W[i];
    if (t < 32) { asv[t] = a_src[t]; adv[t] = a_dst[t]; }
    for (int i = t; i < 2048; i += 256) {
        int row = i >> 5, seg = i & 31;
        float4 v = make_float4(0.f, 0.f, 0.f, 0.f);
        if (rb + row < n)
            v = ((const float4*)(x + (size_t)(rb + row) * 128))[seg];
        int c = seg * 4;
        xs[row][c + 0] = v.x; xs[row][c + 1] = v.y;
        xs[row][c + 2] = v.z; xs[row][c + 3] = v.w;
    }
    __syncthreads();

    int tr = t >> 3;
    int tc = t & 7;
    float acc[2][4];
#pragma unroll
    for (int i = 0; i < 2; i++)
#pragma unroll
        for (int j = 0; j < 4; j++) acc[i][j] = 0.f;

#pragma unroll 4
    for (int k = 0; k < 128; k++) {
        float x0 = xs[tr][k];
        float x1 = xs[tr + 32][k];
        float4 wv = *(const float4*)&Wl[k][tc * 4];
        acc[0][0] += x0 * wv.x; acc[0][1] += x0 * wv.y;
        acc[0][2] += x0 * wv.z; acc[0][3] += x0 * wv.w;
        acc[1][0] += x1 * wv.x; acc[1][1] += x1 * wv.y;
        acc[1][2] += x1 * wv.z; acc[1][3] += x1 * wv.w;
    }

#pragma unroll
    for (int i = 0; i < 2; i++) {
        int r = rb + tr + i * 32;
        if (r < n) {
            *(float4*)&h[(size_t)r * 32 + tc * 4] =
                make_float4(acc[i][0], acc[i][1], acc[i][2], acc[i][3]);
        }
        float ps = 0.f, pd = 0.f;
#pragma unroll
        for (int j = 0; j < 4; j++) {
            int c = tc * 4 + j;
            ps += acc[i][j] * asv[c];
            pd += acc[i][j] * adv[c];
        }
        for (int m = 1; m < 8; m <<= 1) {
            ps += __shfl_xor(ps, m, 64);
            pd += __shfl_xor(pd, m, 64);
        }
        if (tc == 0 && r < n) { as_[r] = ps; ad_[r] = pd; }
    }
}

// ---------------- CSR build (partition-first, zero device atomics) --------
// pairs packed u32: (d - window_base) << 17 | src  (src<2^17, dloc<2^9)
#define PCHUNK 4096
#define NW 256
__global__ __launch_bounds__(256) void partition_kernel(
    const int* __restrict__ srcI, const int* __restrict__ dstI,
    u32* __restrict__ pairs, u32* __restrict__ bcur,
    int E, int wsz, int cap)
{
    __shared__ u32 lcount[NW];
    __shared__ u32 lbase[NW];
    int t = threadIdx.x;
    for (int chunk = blockIdx.x * PCHUNK; chunk < E; chunk += gridDim.x * PCHUNK) {
        lcount[t] = 0;
        __syncthreads();
        u32 pk[16]; int wv[16]; u32 rk[16]; bool val[16];
#pragma unroll
        for (int k = 0; k < 16; k++) {
            int i = chunk + k * 256 + t;
            val[k] = i < E;
            if (val[k]) {
                u32 s = (u32)srcI[i];
                u32 d = (u32)dstI[i];
                wv[k] = d / (u32)wsz;
                u32 dloc = d - (u32)wv[k] * (u32)wsz;
                pk[k] = (dloc << 17) | s;
                rk[k] = atomicAdd(&lcount[wv[k]], 1u);
            }
        }
        __syncthreads();
        if (lcount[t] > 0)
            lbase[t] = atomicAdd(&bcur[t], lcount[t]);
        __syncthreads();
#pragma unroll
        for (int k = 0; k < 16; k++) {
            if (val[k]) {
                u32 pos = lbase[wv[k]] + rk[k];
                if (pos < (u32)cap)   // overflow guard (P ~ 0, 39 sigma)
                    pairs[(size_t)wv[k] * cap + pos] = pk[k];
            }
        }
        __syncthreads();
    }
}

// One block per window: LDS histogram -> plain deg stores.
__global__ __launch_bounds__(256) void hist_kernel(
    const u32* __restrict__ pairs, const u32* __restrict__ bcur,
    u32* __restrict__ deg, int n, int wsz, int cap)
{
    __shared__ u32 dw[512];
    int grp = blockIdx.x;
    int t = threadIdx.x;
    for (int i = t; i < wsz; i += 256) dw[i] = 0;
    __syncthreads();
    u32 cnt = bcur[grp]; if (cnt > (u32)cap) cnt = (u32)cap;
    size_t base = (size_t)grp * cap;
    for (u32 i = t; i < cnt; i += 256)
        atomicAdd(&dw[pairs[base + i] >> 17], 1u);
    __syncthreads();
    int wlo = grp * wsz;
    for (int i = t; i < wsz; i += 256) {
        int g = wlo + i;
        if (g < n) deg[g] = dw[i];
    }
}

__global__ __launch_bounds__(256) void scan_bsum_kernel(
    const u32* __restrict__ deg, u32* __restrict__ bsum, int n)
{
    __shared__ u32 red[256];
    int b = blockIdx.x, t = threadIdx.x;
    int base = b * 2048;
    u32 local = 0;
    for (int i = t; i < 2048; i += 256) {
        int g = base + i;
        local += (g < n) ? deg[g] + 1u : 0u;
    }
    red[t] = local; __syncthreads();
    for (int o = 128; o > 0; o >>= 1) {
        if (t < o) red[t] += red[t + o];
        __syncthreads();
    }
    if (t == 0) bsum[b] = red[0];
}

__global__ void scan_partials_kernel(u32* bsum, int nb)
{
    if (threadIdx.x == 0) {
        u32 run = 0;
        for (int i = 0; i < nb; i++) { u32 v = bsum[i]; bsum[i] = run; run += v; }
    }
}

// writes rowS and the self-loop srcS slot (last slot of segment).
__global__ __launch_bounds__(256) void scan_write_kernel(
    const u32* __restrict__ deg, const u32* __restrict__ bsum,
    u32* __restrict__ rowS, int* __restrict__ srcS, int n)
{
    __shared__ u32 tsum[256];
    int b = blockIdx.x, t = threadIdx.x;
    int base = b * 2048 + t * 8;
    u32 v[8]; u32 loc = 0;
#pragma unroll
    for (int k = 0; k < 8; k++) {
        int g = base + k;
        v[k] = (g < n) ? deg[g] + 1u : 0u;
        loc += v[k];
    }
    tsum[t] = loc; __syncthreads();
    for (int o = 1; o < 256; o <<= 1) {
        u32 y = (t >= o) ? tsum[t - o] : 0u;
        __syncthreads();
        tsum[t] += y;
        __syncthreads();
    }
    u32 off = bsum[b] + tsum[t] - loc;   // exclusive
#pragma unroll
    for (int k = 0; k < 8; k++) {
        int g = base + k;
        if (g < n) {
            rowS[g] = off;
            srcS[off + v[k] - 1u] = g;   // self-loop at last slot
        }
        off += v[k];
    }
}

// Phase B: one block per window owns cur[] in LDS -> no device atomics.
__global__ __launch_bounds__(256) void scatter_kernel(
    const u32* __restrict__ pairs, const u32* __restrict__ bcur,
    const u32* __restrict__ rowS,
    int* __restrict__ srcS, int n, int wsz, int cap)
{
    __shared__ u32 cw[512];
    int grp = blockIdx.x;
    int t = threadIdx.x;
    int wlo = grp * wsz;
    for (int i = t; i < wsz; i += 256) {
        int g = wlo + i;
        cw[i] = (g < n) ? rowS[g] : 0u;
    }
    __syncthreads();
    u32 cnt = bcur[grp]; if (cnt > (u32)cap) cnt = (u32)cap;
    size_t base = (size_t)grp * cap;
    for (u32 i = t; i < cnt; i += 256) {
        u32 pr = pairs[base + i];
        u32 pos = atomicAdd(&cw[pr >> 17], 1u);
        srcS[pos] = (int)(pr & 0x1FFFFu);
    }
}

// ---------------- layer-1 fused softmax+aggregate (no-max softmax) ---------
// Shuffle-free edge loop: lane = e8*8 + q; each lane directly loads its
// edge's srcS / as_ (8 q-lanes share the address -> one coalesced request)
// and computes exp redundantly per lane-group. Partial sums live per-lane;
// a single 3-step e8-reduce (masks 8/16/32) at the end. No ds_bpermute in
// the dependence chain, all 64 lanes useful every iteration.
__global__ __launch_bounds__(256) void l1_fused_kernel(
    const u32* __restrict__ rowS, const u32* __restrict__ deg,
    const int* __restrict__ srcS,
    const float* __restrict__ as_, const float* __restrict__ ad_,
    const float* __restrict__ h, const float* __restrict__ b1,
    float* __restrict__ h1r, int n)
{
    int d = (blockIdx.x * 256 + threadIdx.x) >> 6;
    int lane = threadIdx.x & 63;
    if (d >= n) return;
    int beg = (int)rowS[d];
    int end = beg + (int)deg[d] + 1;
    float adv = ad_[d];
    int e8 = lane >> 3;
    int q  = lane & 7;

    float sum = 0.f;
    float4 acc = make_float4(0.f, 0.f, 0.f, 0.f);
    for (int j0 = beg; j0 < end; j0 += 8) {
        int j = j0 + e8;
        bool v = j < end;
        int s = v ? srcS[j] : 0;
        float p = v ? __expf(fminf(lrelu(as_[s] + adv), 60.f)) : 0.f;
        sum += p;
        float4 hv = ((const float4*)(h + (size_t)s * 32))[q];
        acc.x += p * hv.x; acc.y += p * hv.y;
        acc.z += p * hv.z; acc.w += p * hv.w;
    }
    for (int o = 8; o < 64; o <<= 1) {
        sum   += __shfl_xor(sum, o, 64);
        acc.x += __shfl_xor(acc.x, o, 64);
        acc.y += __shfl_xor(acc.y, o, 64);
        acc.z += __shfl_xor(acc.z, o, 64);
        acc.w += __shfl_xor(acc.w, o, 64);
    }
    if (lane < 8) {                     // e8 == 0, q = lane
        float inv = 1.f / sum;
        float4 r;
        r.x = fmaxf(acc.x * inv + b1[4 * lane + 0], 0.f);
        r.y = fmaxf(acc.y * inv + b1[4 * lane + 1], 0.f);
        r.z = fmaxf(acc.z * inv + b1[4 * lane + 2], 0.f);
        r.w = fmaxf(acc.w * inv + b1[4 * lane + 3], 0.f);
        *(float4*)&h1r[(size_t)d * 32 + 4 * lane] = r;
    }
}

// ---------------- GEMM2: h1r @ {W_mu, W_ls} -> fp32 interleaved hmhl -------
__global__ __launch_bounds__(256) void gemm2_kernel(
    const float* __restrict__ h1r,
    const float* __restrict__ Wm, const float* __restrict__ Wl_,
    const float* __restrict__ ams, const float* __restrict__ amd,
    const float* __restrict__ alsb, const float* __restrict__ ald,
    float* __restrict__ hmhl, float2* __restrict__ attn2,
    float* __restrict__ amud, float* __restrict__ alsd, int n)
{
    __shared__ float hs[16][33];
    __shared__ float Wms[32][16], Wls[32][16];
    __shared__ float amsv[16], amdv[16], alsv[16], aldv[16];
    int t = threadIdx.x;
    int rb = blockIdx.x * 16;

    for (int i = t; i < 512; i += 256) {
        int k = i >> 4, c = i & 15;
        Wms[k][c] = Wm[i];
        Wls[k][c] = Wl_[i];
    }
    if (t < 16) {
        amsv[t] = ams[t]; amdv[t] = amd[t];
        alsv[t] = alsb[t]; aldv[t] = ald[t];
    }
    for (int i = t; i < 512; i += 256) {
        int r = i >> 5, k = i & 31;
        int gr = rb + r;
        hs[r][k] = (gr < n) ? h1r[(size_t)gr * 32 + k] : 0.f;
    }
    __syncthreads();

    int tr = t >> 4;
    int c = t & 15;
    float accm = 0.f, accl = 0.f;
#pragma unroll
    for (int k = 0; k < 32; k++) {
        float hv = hs[tr][k];
        accm += hv * Wms[k][c];
        accl += hv * Wls[k][c];
    }
    int r = rb + tr;
    if (r < n) {
        hmhl[(size_t)r * 32 + c]      = accm;
        hmhl[(size_t)r * 32 + 16 + c] = accl;
    }
    float pms = accm * amsv[c], pmd = accm * amdv[c];
    float pls = accl * alsv[c], pld = accl * aldv[c];
    for (int m = 1; m < 16; m <<= 1) {
        pms += __shfl_xor(pms, m, 64);
        pmd += __shfl_xor(pmd, m, 64);
        pls += __shfl_xor(pls, m, 64);
        pld += __shfl_xor(pld, m, 64);
    }
    if (c == 0 && r < n) {
        attn2[r] = make_float2(pms, pls);
        amud[r] = pmd;
        alsd[r] = pld;
    }
}

// ---------------- layer-2 fused (mu & ls, no-max) + bias -> out -------------
// Same shuffle-free structure. Each lane computes only the exp it needs
// (q<4 -> pm, q>=4 -> pl): ssum carries s_m in q<4 lanes, s_l in q>=4 lanes;
// the e8-reduce never mixes q slices (masks touch lane bits 3..5 only).
__global__ __launch_bounds__(256) void l2_fused_kernel(
    const u32* __restrict__ rowS, const u32* __restrict__ deg,
    const int* __restrict__ srcS,
    const float2* __restrict__ attn2,
    const float* __restrict__ amud, const float* __restrict__ alsd,
    const float* __restrict__ hmhl,
    const float* __restrict__ bm, const float* __restrict__ bl,
    float* __restrict__ out, int n)
{
    int d = (blockIdx.x * 256 + threadIdx.x) >> 6;
    int lane = threadIdx.x & 63;
    if (d >= n) return;
    int beg = (int)rowS[d];
    int end = beg + (int)deg[d] + 1;
    float amdv = amud[d], aldv = alsd[d];
    int e8 = lane >> 3;
    int q  = lane & 7;
    bool isMu = q < 4;
    float addv = isMu ? amdv : aldv;

    float ssum = 0.f;
    float4 acc = make_float4(0.f, 0.f, 0.f, 0.f);

    for (int j0 = beg; j0 < end; j0 += 8) {
        int j = j0 + e8;
        bool v = j < end;
        int s = v ? srcS[j] : 0;
        float2 a2 = attn2[s];
        float logit = (isMu ? a2.x : a2.y) + addv;
        float p = v ? __expf(fminf(lrelu(logit), 60.f)) : 0.f;
        ssum += p;
        float4 hv = ((const float4*)(hmhl + (size_t)s * 32))[q];
        acc.x += p * hv.x; acc.y += p * hv.y;
        acc.z += p * hv.z; acc.w += p * hv.w;
    }
    for (int o = 8; o < 64; o <<= 1) {
        ssum  += __shfl_xor(ssum, o, 64);
        acc.x += __shfl_xor(acc.x, o, 64);
        acc.y += __shfl_xor(acc.y, o, 64);
        acc.z += __shfl_xor(acc.z, o, 64);
        acc.w += __shfl_xor(acc.w, o, 64);
    }
    if (lane < 8) {                     // e8 == 0, q = lane
        float inv = 1.f / ssum;
        if (lane < 4) {
            float4 r;
            r.x = acc.x * inv + bm[4 * lane + 0];
            r.y = acc.y * inv + bm[4 * lane + 1];
            r.z = acc.z * inv + bm[4 * lane + 2];
            r.w = acc.w * inv + bm[4 * lane + 3];
            *(float4*)&out[(size_t)d * 16 + 4 * lane] = r;
        } else {
            int qc = 4 * (lane - 4);
            float4 r;
            r.x = acc.x * inv + bl[qc + 0];
            r.y = acc.y * inv + bl[qc + 1];
            r.z = acc.z * inv + bl[qc + 2];
            r.w = acc.w * inv + bl[qc + 3];
            *(float4*)&out[(size_t)n * 16 + (size_t)d * 16 + qc] = r;
        }
    }
}

extern "C" void kernel_launch(void* const* d_in, const int* in_sizes, int n_in,
                              void* d_out, int out_size, void* d_ws, size_t ws_size,
                              hipStream_t stream)
{
    const float* x   = (const float*)d_in[0];
    const int*   ei  = (const int*)d_in[1];
    const float* W1  = (const float*)d_in[2];
    const float* a1s = (const float*)d_in[3];
    const float* a1d = (const float*)d_in[4];
    const float* b1  = (const float*)d_in[5];
    const float* Wm  = (const float*)d_in[6];
    const float* ams = (const float*)d_in[7];
    const float* amd = (const float*)d_in[8];
    const float* bm  = (const float*)d_in[9];
    const float* Wl  = (const float*)d_in[10];
    const float* als = (const float*)d_in[11];
    const float* ald = (const float*)d_in[12];
    const float* bl  = (const float*)d_in[13];

    int n  = in_sizes[0] / 128;
    int E  = in_sizes[1] / 2;
    int Et = E + n;
    int wsz = (n + NW - 1) / NW;          // 391 for n=100000 (fits 9 bits)
    int cap = E / NW + 3072;              // 39-sigma slack
    const int* srcI = ei;
    const int* dstI = ei + E;

    float* ws = (float*)d_ws;
    // Layout (floats), peak ~ 71n + Et + 300 ≈ 35.5 MB:
    //  [0,32n)    h (fp32)   -> reused by hmhl after l1
    //  [32n,64n)  h1r        -> aliased by pairs (u32 x NW*cap = 9.5MB) BEFORE l1
    //  [64n,66n)  as_,ad_    -> attn2 (float2) after l1
    //  [66n,67n)  amud ; [67n,68n) alsd
    //  [68n,69n)  deg | [69n,69n+NW) bcur | [70n,71n) rowS
    //  [71n,71n+Et) srcS ; then bsum(256)
    float*  h    = ws;
    float*  hmhl = ws;
    float*  h1r  = ws + (size_t)32 * n;
    u32*    pairs = (u32*)(ws + (size_t)32 * n);
    float*  as_  = ws + (size_t)64 * n;
    float*  ad_  = ws + (size_t)65 * n;
    float2* attn2 = (float2*)(ws + (size_t)64 * n);
    float*  amud = ws + (size_t)66 * n;
    float*  alsd = ws + (size_t)67 * n;
    u32*    deg  = (u32*)(ws + (size_t)68 * n);
    u32*    bcur = (u32*)(ws + (size_t)69 * n);
    u32*    rowS = (u32*)(ws + (size_t)70 * n);
    int*    srcS = (int*)(ws + (size_t)71 * n);
    u32*    bsum = (u32*)(ws + (size_t)71 * n + Et);

    int nb = (n + 2047) / 2048;
    int pgrid = (E + PCHUNK - 1) / PCHUNK;

    hipMemsetAsync(bcur, 0, NW * sizeof(u32), stream);

    gemm1_kernel<<<(n + 63) / 64, 256, 0, stream>>>(x, W1, a1s, a1d, h, as_, ad_, n);

    partition_kernel<<<pgrid, 256, 0, stream>>>(srcI, dstI, pairs, bcur, E, wsz, cap);
    hist_kernel<<<NW, 256, 0, stream>>>(pairs, bcur, deg, n, wsz, cap);
    scan_bsum_kernel<<<nb, 256, 0, stream>>>(deg, bsum, n);
    scan_partials_kernel<<<1, 64, 0, stream>>>(bsum, nb);
    scan_write_kernel<<<nb, 256, 0, stream>>>(deg, bsum, rowS, srcS, n);
    scatter_kernel<<<NW, 256, 0, stream>>>(pairs, bcur, rowS, srcS, n, wsz, cap);

    l1_fused_kernel<<<(n + 3) / 4, 256, 0, stream>>>(rowS, deg, srcS, as_, ad_,
                                                     h, b1, h1r, n);

    gemm2_kernel<<<(n + 15) / 16, 256, 0, stream>>>(h1r, Wm, Wl, ams, amd, als, ald,
                                                    hmhl, attn2, amud, alsd, n);

    l2_fused_kernel<<<(n + 3) / 4, 256, 0, stream>>>(rowS, deg, srcS,
                                                     attn2, amud, alsd,
                                                     hmhl, bm, bl,
                                                     (float*)d_out, n);
}

// Round 5
// 299.500 us; speedup vs baseline: 1.1061x; 1.1061x over previous
//
#include <hip/hip_runtime.h>
#include <hip/hip_bf16.h>

typedef unsigned int u32;
typedef unsigned short u16;

__device__ __forceinline__ float lrelu(float v) {
    return v > 0.f ? v : 0.2f * v;
}

// ---------------- GEMM1: h = x @ W1  [n,128]x[128,32], + row dots ----------
__global__ __launch_bounds__(256) void gemm1_kernel(
    const float* __restrict__ x, const float* __restrict__ W,
    const float* __restrict__ a_src, const float* __restrict__ a_dst,
    float* __restrict__ h, float* __restrict__ as_, float* __restrict__ ad_,
    int n)
{
    __shared__ float xs[64][132];
    __shared__ float Wl[128][32];
    __shared__ float asv[32], adv[32];
    int t = threadIdx.x;
    int rb = blockIdx.x * 64;

    for (int i = t; i < 4096; i += 256) Wl[i >> 5][i & 31] = W[i];
    if (t < 32) { asv[t] = a_src[t]; adv[t] = a_dst[t]; }
    for (int i = t; i < 2048; i += 256) {
        int row = i >> 5, seg = i & 31;
        float4 v = make_float4(0.f, 0.f, 0.f, 0.f);
        if (rb + row < n)
            v = ((const float4*)(x + (size_t)(rb + row) * 128))[seg];
        int c = seg * 4;
        xs[row][c + 0] = v.x; xs[row][c + 1] = v.y;
        xs[row][c + 2] = v.z; xs[row][c + 3] = v.w;
    }
    __syncthreads();

    int tr = t >> 3;
    int tc = t & 7;
    float acc[2][4];
#pragma unroll
    for (int i = 0; i < 2; i++)
#pragma unroll
        for (int j = 0; j < 4; j++) acc[i][j] = 0.f;

#pragma unroll 4
    for (int k = 0; k < 128; k++) {
        float x0 = xs[tr][k];
        float x1 = xs[tr + 32][k];
        float4 wv = *(const float4*)&Wl[k][tc * 4];
        acc[0][0] += x0 * wv.x; acc[0][1] += x0 * wv.y;
        acc[0][2] += x0 * wv.z; acc[0][3] += x0 * wv.w;
        acc[1][0] += x1 * wv.x; acc[1][1] += x1 * wv.y;
        acc[1][2] += x1 * wv.z; acc[1][3] += x1 * wv.w;
    }

#pragma unroll
    for (int i = 0; i < 2; i++) {
        int r = rb + tr + i * 32;
        if (r < n) {
            *(float4*)&h[(size_t)r * 32 + tc * 4] =
                make_float4(acc[i][0], acc[i][1], acc[i][2], acc[i][3]);
        }
        float ps = 0.f, pd = 0.f;
#pragma unroll
        for (int j = 0; j < 4; j++) {
            int c = tc * 4 + j;
            ps += acc[i][j] * asv[c];
            pd += acc[i][j] * adv[c];
        }
        for (int m = 1; m < 8; m <<= 1) {
            ps += __shfl_xor(ps, m, 64);
            pd += __shfl_xor(pd, m, 64);
        }
        if (tc == 0 && r < n) { as_[r] = ps; ad_[r] = pd; }
    }
}

// ---------------- CSR build (partition-first, zero device atomics) --------
// pairs packed u32: (d - window_base) << 17 | src  (src<2^17, dloc<2^9)
#define PCHUNK 4096
#define NW 256
__global__ __launch_bounds__(256) void partition_kernel(
    const int* __restrict__ srcI, const int* __restrict__ dstI,
    u32* __restrict__ pairs, u32* __restrict__ bcur,
    int E, int wsz, int cap)
{
    __shared__ u32 lcount[NW];
    __shared__ u32 lbase[NW];
    int t = threadIdx.x;
    for (int chunk = blockIdx.x * PCHUNK; chunk < E; chunk += gridDim.x * PCHUNK) {
        lcount[t] = 0;
        __syncthreads();
        u32 pk[16]; int wv[16]; u32 rk[16]; bool val[16];
#pragma unroll
        for (int k = 0; k < 16; k++) {
            int i = chunk + k * 256 + t;
            val[k] = i < E;
            if (val[k]) {
                u32 s = (u32)srcI[i];
                u32 d = (u32)dstI[i];
                wv[k] = d / (u32)wsz;
                u32 dloc = d - (u32)wv[k] * (u32)wsz;
                pk[k] = (dloc << 17) | s;
                rk[k] = atomicAdd(&lcount[wv[k]], 1u);
            }
        }
        __syncthreads();
        if (lcount[t] > 0)
            lbase[t] = atomicAdd(&bcur[t], lcount[t]);
        __syncthreads();
#pragma unroll
        for (int k = 0; k < 16; k++) {
            if (val[k]) {
                u32 pos = lbase[wv[k]] + rk[k];
                if (pos < (u32)cap)   // overflow guard (P ~ 0, 39 sigma)
                    pairs[(size_t)wv[k] * cap + pos] = pk[k];
            }
        }
        __syncthreads();
    }
}

// window totals -> exclusive window bases. total(g) = min(bcur,cap) + wnodes
// (self-loops), so no deg pass is needed. 1 block, 256 threads.
__global__ void wbase_kernel(const u32* __restrict__ bcur,
                             u32* __restrict__ wbase, int n, int wsz, int cap)
{
    __shared__ u32 ts[NW];
    int t = threadIdx.x;
    int wlo = t * wsz;
    int wnodes = n - wlo; if (wnodes < 0) wnodes = 0; if (wnodes > wsz) wnodes = wsz;
    u32 cnt = bcur[t]; if (cnt > (u32)cap) cnt = (u32)cap;
    u32 tot = cnt + (u32)wnodes;
    ts[t] = tot; __syncthreads();
    for (int o = 1; o < NW; o <<= 1) {
        u32 y = (t >= o) ? ts[t - o] : 0u;
        __syncthreads();
        ts[t] += y;
        __syncthreads();
    }
    wbase[t] = ts[t] - tot;   // exclusive
}

// Fused CSR epilogue: one block per window. Pass 1: LDS hist from slab.
// Local 512-entry scan -> rowS/deg/self-loop stores (plain; exclusive window
// ownership). Pass 2: scatter with LDS cur (slab re-read hits L2, ~25KB).
// Replaces hist/scan_bsum/scan_partials/scan_write/scatter (5 kernels -> 1).
__global__ __launch_bounds__(256) void csr_window_kernel(
    const u32* __restrict__ pairs, const u32* __restrict__ bcur,
    const u32* __restrict__ wbase,
    u32* __restrict__ rowS, u32* __restrict__ deg, int* __restrict__ srcS,
    int n, int wsz, int cap)
{
    __shared__ u32 dw[512];
    __shared__ u32 cw[512];
    __shared__ u32 ts[256];
    int grp = blockIdx.x;
    int t = threadIdx.x;
    int wlo = grp * wsz;
    int wnodes = n - wlo; if (wnodes < 0) wnodes = 0; if (wnodes > wsz) wnodes = wsz;
    u32 cnt = bcur[grp]; if (cnt > (u32)cap) cnt = (u32)cap;
    size_t base = (size_t)grp * cap;

    dw[t] = 0; dw[t + 256] = 0;
    __syncthreads();
    for (u32 i = t; i < cnt; i += 256)
        atomicAdd(&dw[pairs[base + i] >> 17], 1u);
    __syncthreads();

    // local scan over 512 slots (2 per thread), seeded with window base
    int i0 = 2 * t, i1 = 2 * t + 1;
    u32 e0 = (i0 < wnodes) ? dw[i0] + 1u : 0u;
    u32 e1 = (i1 < wnodes) ? dw[i1] + 1u : 0u;
    ts[t] = e0 + e1;
    __syncthreads();
    for (int o = 1; o < 256; o <<= 1) {
        u32 y = (t >= o) ? ts[t - o] : 0u;
        __syncthreads();
        ts[t] += y;
        __syncthreads();
    }
    u32 off = wbase[grp] + ts[t] - (e0 + e1);   // exclusive
    if (i0 < wnodes) {
        u32 dgi = dw[i0];
        cw[i0] = off;
        rowS[wlo + i0] = off;
        deg[wlo + i0] = dgi;
        srcS[off + dgi] = wlo + i0;      // self-loop at last slot
    }
    u32 off1 = off + e0;
    if (i1 < wnodes) {
        u32 dgi = dw[i1];
        cw[i1] = off1;
        rowS[wlo + i1] = off1;
        deg[wlo + i1] = dgi;
        srcS[off1 + dgi] = wlo + i1;
    }
    __syncthreads();

    // scatter (slab is L2-hot from pass 1)
    for (u32 i = t; i < cnt; i += 256) {
        u32 pr = pairs[base + i];
        u32 pos = atomicAdd(&cw[pr >> 17], 1u);
        srcS[pos] = (int)(pr & 0x1FFFFu);
    }
}

// ---------------- layer-1 fused softmax+aggregate (no-max softmax) ---------
// R3 structure (measured best): tile of 64 edges; edge phase loads srcS/as_
// once per tile; inner loop distributes 8 edges x 8 quads via shuffles so
// gathers are independent; sum reduce deferred to the end.
__global__ __launch_bounds__(256) void l1_fused_kernel(
    const u32* __restrict__ rowS, const u32* __restrict__ deg,
    const int* __restrict__ srcS,
    const float* __restrict__ as_, const float* __restrict__ ad_,
    const float* __restrict__ h, const float* __restrict__ b1,
    float* __restrict__ h1r, int n)
{
    int d = (blockIdx.x * 256 + threadIdx.x) >> 6;
    int lane = threadIdx.x & 63;
    if (d >= n) return;
    int beg = (int)rowS[d];
    int end = beg + (int)deg[d] + 1;
    float adv = ad_[d];
    int e8 = lane >> 3;
    int q  = lane & 7;

    float sum = 0.f;
    float4 acc = make_float4(0.f, 0.f, 0.f, 0.f);
    for (int base = beg; base < end; base += 64) {
        int j = base + lane;
        bool valid = j < end;
        int s = valid ? srcS[j] : 0;
        float p = valid ? __expf(fminf(lrelu(as_[s] + adv), 60.f)) : 0.f;
        sum += p;                       // cross-lane reduce deferred to end
        int cnt = end - base; if (cnt > 64) cnt = 64;
        for (int jj = 0; jj < cnt; jj += 8) {
            int idx = jj + e8;
            int sj   = __shfl(s, idx, 64);
            float w  = __shfl(p, idx, 64);
            if (idx >= cnt) w = 0.f;    // convergent kill, row 0 broadcast
            float4 hv = ((const float4*)(h + (size_t)sj * 32))[q];
            acc.x += w * hv.x; acc.y += w * hv.y;
            acc.z += w * hv.z; acc.w += w * hv.w;
        }
    }
    for (int o = 32; o > 0; o >>= 1) sum += __shfl_xor(sum, o, 64);
    for (int o = 8; o < 64; o <<= 1) {
        acc.x += __shfl_xor(acc.x, o, 64);
        acc.y += __shfl_xor(acc.y, o, 64);
        acc.z += __shfl_xor(acc.z, o, 64);
        acc.w += __shfl_xor(acc.w, o, 64);
    }
    if (lane < 8) {
        float inv = 1.f / sum;
        float4 r;
        r.x = fmaxf(acc.x * inv + b1[4 * lane + 0], 0.f);
        r.y = fmaxf(acc.y * inv + b1[4 * lane + 1], 0.f);
        r.z = fmaxf(acc.z * inv + b1[4 * lane + 2], 0.f);
        r.w = fmaxf(acc.w * inv + b1[4 * lane + 3], 0.f);
        *(float4*)&h1r[(size_t)d * 32 + 4 * lane] = r;
    }
}

// ---------------- GEMM2: h1r @ {W_mu, W_ls} -> fp32 interleaved hmhl -------
__global__ __launch_bounds__(256) void gemm2_kernel(
    const float* __restrict__ h1r,
    const float* __restrict__ Wm, const float* __restrict__ Wl_,
    const float* __restrict__ ams, const float* __restrict__ amd,
    const float* __restrict__ alsb, const float* __restrict__ ald,
    float* __restrict__ hmhl, float2* __restrict__ attn2,
    float* __restrict__ amud, float* __restrict__ alsd, int n)
{
    __shared__ float hs[16][33];
    __shared__ float Wms[32][16], Wls[32][16];
    __shared__ float amsv[16], amdv[16], alsv[16], aldv[16];
    int t = threadIdx.x;
    int rb = blockIdx.x * 16;

    for (int i = t; i < 512; i += 256) {
        int k = i >> 4, c = i & 15;
        Wms[k][c] = Wm[i];
        Wls[k][c] = Wl_[i];
    }
    if (t < 16) {
        amsv[t] = ams[t]; amdv[t] = amd[t];
        alsv[t] = alsb[t]; aldv[t] = ald[t];
    }
    for (int i = t; i < 512; i += 256) {
        int r = i >> 5, k = i & 31;
        int gr = rb + r;
        hs[r][k] = (gr < n) ? h1r[(size_t)gr * 32 + k] : 0.f;
    }
    __syncthreads();

    int tr = t >> 4;
    int c = t & 15;
    float accm = 0.f, accl = 0.f;
#pragma unroll
    for (int k = 0; k < 32; k++) {
        float hv = hs[tr][k];
        accm += hv * Wms[k][c];
        accl += hv * Wls[k][c];
    }
    int r = rb + tr;
    if (r < n) {
        hmhl[(size_t)r * 32 + c]      = accm;
        hmhl[(size_t)r * 32 + 16 + c] = accl;
    }
    float pms = accm * amsv[c], pmd = accm * amdv[c];
    float pls = accl * alsv[c], pld = accl * aldv[c];
    for (int m = 1; m < 16; m <<= 1) {
        pms += __shfl_xor(pms, m, 64);
        pmd += __shfl_xor(pmd, m, 64);
        pls += __shfl_xor(pls, m, 64);
        pld += __shfl_xor(pld, m, 64);
    }
    if (c == 0 && r < n) {
        attn2[r] = make_float2(pms, pls);
        amud[r] = pmd;
        alsd[r] = pld;
    }
}

// ---------------- layer-2 fused (mu & ls, no-max) + bias -> out -------------
// R3 structure: q<4 -> mu quad, q>=4 -> ls quad; row hmhl[s] = [mu16|ls16].
__global__ __launch_bounds__(256) void l2_fused_kernel(
    const u32* __restrict__ rowS, const u32* __restrict__ deg,
    const int* __restrict__ srcS,
    const float2* __restrict__ attn2,
    const float* __restrict__ amud, const float* __restrict__ alsd,
    const float* __restrict__ hmhl,
    const float* __restrict__ bm, const float* __restrict__ bl,
    float* __restrict__ out, int n)
{
    int d = (blockIdx.x * 256 + threadIdx.x) >> 6;
    int lane = threadIdx.x & 63;
    if (d >= n) return;
    int beg = (int)rowS[d];
    int end = beg + (int)deg[d] + 1;
    float amdv = amud[d], aldv = alsd[d];
    int e8 = lane >> 3;
    int q  = lane & 7;
    bool isMu = q < 4;

    float s_m = 0.f, s_l = 0.f;
    float4 acc = make_float4(0.f, 0.f, 0.f, 0.f);

    for (int base = beg; base < end; base += 64) {
        int j = base + lane;
        bool valid = j < end;
        int s = valid ? srcS[j] : 0;
        float2 a2 = valid ? attn2[s] : make_float2(0.f, 0.f);
        float pm = valid ? __expf(fminf(lrelu(a2.x + amdv), 60.f)) : 0.f;
        float pl = valid ? __expf(fminf(lrelu(a2.y + aldv), 60.f)) : 0.f;
        s_m += pm;
        s_l += pl;
        int cnt = end - base; if (cnt > 64) cnt = 64;
        for (int jj = 0; jj < cnt; jj += 8) {
            int idx = jj + e8;
            int sj    = __shfl(s, idx, 64);
            float pmj = __shfl(pm, idx, 64);
            float plj = __shfl(pl, idx, 64);
            float w = isMu ? pmj : plj;
            if (idx >= cnt) w = 0.f;
            float4 hv = ((const float4*)(hmhl + (size_t)sj * 32))[q];
            acc.x += w * hv.x; acc.y += w * hv.y;
            acc.z += w * hv.z; acc.w += w * hv.w;
        }
    }
    for (int o = 32; o > 0; o >>= 1) {
        s_m += __shfl_xor(s_m, o, 64);
        s_l += __shfl_xor(s_l, o, 64);
    }
    for (int o = 8; o < 64; o <<= 1) {
        acc.x += __shfl_xor(acc.x, o, 64);
        acc.y += __shfl_xor(acc.y, o, 64);
        acc.z += __shfl_xor(acc.z, o, 64);
        acc.w += __shfl_xor(acc.w, o, 64);
    }
    if (lane < 8) {
        if (lane < 4) {
            float inv = 1.f / s_m;
            float4 r;
            r.x = acc.x * inv + bm[4 * lane + 0];
            r.y = acc.y * inv + bm[4 * lane + 1];
            r.z = acc.z * inv + bm[4 * lane + 2];
            r.w = acc.w * inv + bm[4 * lane + 3];
            *(float4*)&out[(size_t)d * 16 + 4 * lane] = r;
        } else {
            float inv = 1.f / s_l;
            int qc = 4 * (lane - 4);
            float4 r;
            r.x = acc.x * inv + bl[qc + 0];
            r.y = acc.y * inv + bl[qc + 1];
            r.z = acc.z * inv + bl[qc + 2];
            r.w = acc.w * inv + bl[qc + 3];
            *(float4*)&out[(size_t)n * 16 + (size_t)d * 16 + qc] = r;
        }
    }
}

extern "C" void kernel_launch(void* const* d_in, const int* in_sizes, int n_in,
                              void* d_out, int out_size, void* d_ws, size_t ws_size,
                              hipStream_t stream)
{
    const float* x   = (const float*)d_in[0];
    const int*   ei  = (const int*)d_in[1];
    const float* W1  = (const float*)d_in[2];
    const float* a1s = (const float*)d_in[3];
    const float* a1d = (const float*)d_in[4];
    const float* b1  = (const float*)d_in[5];
    const float* Wm  = (const float*)d_in[6];
    const float* ams = (const float*)d_in[7];
    const float* amd = (const float*)d_in[8];
    const float* bm  = (const float*)d_in[9];
    const float* Wl  = (const float*)d_in[10];
    const float* als = (const float*)d_in[11];
    const float* ald = (const float*)d_in[12];
    const float* bl  = (const float*)d_in[13];

    int n  = in_sizes[0] / 128;
    int E  = in_sizes[1] / 2;
    int Et = E + n;
    int wsz = (n + NW - 1) / NW;          // 391 for n=100000 (fits 9 bits, <=512)
    int cap = E / NW + 3072;              // 39-sigma slack
    const int* srcI = ei;
    const int* dstI = ei + E;

    float* ws = (float*)d_ws;
    // Layout (floats), peak ~ 71n + Et + 600 ≈ 35.5 MB:
    //  [0,32n)    h (fp32)   -> reused by hmhl after l1
    //  [32n,64n)  h1r        -> aliased by pairs (u32 x NW*cap = 9.5MB) BEFORE l1
    //  [64n,66n)  as_,ad_    -> attn2 (float2) after l1
    //  [66n,67n)  amud ; [67n,68n) alsd
    //  [68n,69n)  deg | [69n,69n+NW) bcur | [70n,71n) rowS
    //  [71n,71n+Et) srcS ; then wbase(256)
    float*  h    = ws;
    float*  hmhl = ws;
    float*  h1r  = ws + (size_t)32 * n;
    u32*    pairs = (u32*)(ws + (size_t)32 * n);
    float*  as_  = ws + (size_t)64 * n;
    float*  ad_  = ws + (size_t)65 * n;
    float2* attn2 = (float2*)(ws + (size_t)64 * n);
    float*  amud = ws + (size_t)66 * n;
    float*  alsd = ws + (size_t)67 * n;
    u32*    deg  = (u32*)(ws + (size_t)68 * n);
    u32*    bcur = (u32*)(ws + (size_t)69 * n);
    u32*    rowS = (u32*)(ws + (size_t)70 * n);
    int*    srcS = (int*)(ws + (size_t)71 * n);
    u32*    wbase = (u32*)(ws + (size_t)71 * n + Et);

    int pgrid = (E + PCHUNK - 1) / PCHUNK;

    hipMemsetAsync(bcur, 0, NW * sizeof(u32), stream);

    gemm1_kernel<<<(n + 63) / 64, 256, 0, stream>>>(x, W1, a1s, a1d, h, as_, ad_, n);

    partition_kernel<<<pgrid, 256, 0, stream>>>(srcI, dstI, pairs, bcur, E, wsz, cap);
    wbase_kernel<<<1, NW, 0, stream>>>(bcur, wbase, n, wsz, cap);
    csr_window_kernel<<<NW, 256, 0, stream>>>(pairs, bcur, wbase,
                                              rowS, deg, srcS, n, wsz, cap);

    l1_fused_kernel<<<(n + 3) / 4, 256, 0, stream>>>(rowS, deg, srcS, as_, ad_,
                                                     h, b1, h1r, n);

    gemm2_kernel<<<(n + 15) / 16, 256, 0, stream>>>(h1r, Wm, Wl, ams, amd, als, ald,
                                                    hmhl, attn2, amud, alsd, n);

    l2_fused_kernel<<<(n + 3) / 4, 256, 0, stream>>>(rowS, deg, srcS,
                                                     attn2, amud, alsd,
                                                     hmhl, bm, bl,
                                                     (float*)d_out, n);
}

// Round 6
// 293.702 us; speedup vs baseline: 1.1280x; 1.0197x over previous
//
#include <hip/hip_runtime.h>
#include <hip/hip_bf16.h>
#include <hip/hip_fp16.h>

typedef unsigned int u32;
typedef unsigned short u16;

__device__ __forceinline__ float lrelu(float v) {
    return v > 0.f ? v : 0.2f * v;
}

// load quad q (4 halves = 8B) of a 32-half row, convert to float4
__device__ __forceinline__ float4 ldq_h16(const u16* __restrict__ row, int q) {
    uint2 u = ((const uint2*)row)[q];
    __half2 a = *(__half2*)&u.x;
    __half2 b = *(__half2*)&u.y;
    float2 fa = __half22float2(a);
    float2 fb = __half22float2(b);
    return make_float4(fa.x, fa.y, fb.x, fb.y);
}

__device__ __forceinline__ u32 pack2h(float x, float y) {
    __half2 h = __float22half2_rn(make_float2(x, y));
    return *(u32*)&h;
}

// ---------------- GEMM1: h16 = fp16(x @ W1)  [n,128]x[128,32], + row dots --
// h is consumed ONLY by l1's random gather -> store fp16 (64B rows): halves
// gather bytes and nearly fits the 6.4MB table in a 4MB per-XCD L2.
__global__ __launch_bounds__(256) void gemm1_kernel(
    const float* __restrict__ x, const float* __restrict__ W,
    const float* __restrict__ a_src, const float* __restrict__ a_dst,
    u16* __restrict__ h16, float* __restrict__ as_, float* __restrict__ ad_,
    int n)
{
    __shared__ float xs[64][132];
    __shared__ float Wl[128][32];
    __shared__ float asv[32], adv[32];
    int t = threadIdx.x;
    int rb = blockIdx.x * 64;

    for (int i = t; i < 4096; i += 256) Wl[i >> 5][i & 31] = W[i];
    if (t < 32) { asv[t] = a_src[t]; adv[t] = a_dst[t]; }
    for (int i = t; i < 2048; i += 256) {
        int row = i >> 5, seg = i & 31;
        float4 v = make_float4(0.f, 0.f, 0.f, 0.f);
        if (rb + row < n)
            v = ((const float4*)(x + (size_t)(rb + row) * 128))[seg];
        int c = seg * 4;
        xs[row][c + 0] = v.x; xs[row][c + 1] = v.y;
        xs[row][c + 2] = v.z; xs[row][c + 3] = v.w;
    }
    __syncthreads();

    int tr = t >> 3;
    int tc = t & 7;
    float acc[2][4];
#pragma unroll
    for (int i = 0; i < 2; i++)
#pragma unroll
        for (int j = 0; j < 4; j++) acc[i][j] = 0.f;

#pragma unroll 4
    for (int k = 0; k < 128; k++) {
        float x0 = xs[tr][k];
        float x1 = xs[tr + 32][k];
        float4 wv = *(const float4*)&Wl[k][tc * 4];
        acc[0][0] += x0 * wv.x; acc[0][1] += x0 * wv.y;
        acc[0][2] += x0 * wv.z; acc[0][3] += x0 * wv.w;
        acc[1][0] += x1 * wv.x; acc[1][1] += x1 * wv.y;
        acc[1][2] += x1 * wv.z; acc[1][3] += x1 * wv.w;
    }

#pragma unroll
    for (int i = 0; i < 2; i++) {
        int r = rb + tr + i * 32;
        if (r < n) {
            uint2 p;
            p.x = pack2h(acc[i][0], acc[i][1]);
            p.y = pack2h(acc[i][2], acc[i][3]);
            *(uint2*)&h16[(size_t)r * 32 + tc * 4] = p;
        }
        float ps = 0.f, pd = 0.f;
#pragma unroll
        for (int j = 0; j < 4; j++) {
            int c = tc * 4 + j;
            ps += acc[i][j] * asv[c];
            pd += acc[i][j] * adv[c];
        }
        for (int m = 1; m < 8; m <<= 1) {
            ps += __shfl_xor(ps, m, 64);
            pd += __shfl_xor(pd, m, 64);
        }
        if (tc == 0 && r < n) { as_[r] = ps; ad_[r] = pd; }
    }
}

// ---------------- CSR build (partition-first, zero device atomics) --------
// pairs packed u32: (d - window_base) << 17 | src  (src<2^17, dloc<2^9)
#define PCHUNK 4096
#define NW 256
__global__ __launch_bounds__(256) void partition_kernel(
    const int* __restrict__ srcI, const int* __restrict__ dstI,
    u32* __restrict__ pairs, u32* __restrict__ bcur,
    int E, int wsz, int cap)
{
    __shared__ u32 lcount[NW];
    __shared__ u32 lbase[NW];
    int t = threadIdx.x;
    for (int chunk = blockIdx.x * PCHUNK; chunk < E; chunk += gridDim.x * PCHUNK) {
        lcount[t] = 0;
        __syncthreads();
        u32 pk[16]; int wv[16]; u32 rk[16]; bool val[16];
#pragma unroll
        for (int k = 0; k < 16; k++) {
            int i = chunk + k * 256 + t;
            val[k] = i < E;
            if (val[k]) {
                u32 s = (u32)srcI[i];
                u32 d = (u32)dstI[i];
                wv[k] = d / (u32)wsz;
                u32 dloc = d - (u32)wv[k] * (u32)wsz;
                pk[k] = (dloc << 17) | s;
                rk[k] = atomicAdd(&lcount[wv[k]], 1u);
            }
        }
        __syncthreads();
        if (lcount[t] > 0)
            lbase[t] = atomicAdd(&bcur[t], lcount[t]);
        __syncthreads();
#pragma unroll
        for (int k = 0; k < 16; k++) {
            if (val[k]) {
                u32 pos = lbase[wv[k]] + rk[k];
                if (pos < (u32)cap)   // overflow guard (P ~ 0, 39 sigma)
                    pairs[(size_t)wv[k] * cap + pos] = pk[k];
            }
        }
        __syncthreads();
    }
}

// window totals -> exclusive window bases. total(g) = min(bcur,cap) + wnodes
__global__ void wbase_kernel(const u32* __restrict__ bcur,
                             u32* __restrict__ wbase, int n, int wsz, int cap)
{
    __shared__ u32 ts[NW];
    int t = threadIdx.x;
    int wlo = t * wsz;
    int wnodes = n - wlo; if (wnodes < 0) wnodes = 0; if (wnodes > wsz) wnodes = wsz;
    u32 cnt = bcur[t]; if (cnt > (u32)cap) cnt = (u32)cap;
    u32 tot = cnt + (u32)wnodes;
    ts[t] = tot; __syncthreads();
    for (int o = 1; o < NW; o <<= 1) {
        u32 y = (t >= o) ? ts[t - o] : 0u;
        __syncthreads();
        ts[t] += y;
        __syncthreads();
    }
    wbase[t] = ts[t] - tot;   // exclusive
}

// Fused CSR epilogue: hist -> local scan -> rowS/deg/self-loop -> scatter.
__global__ __launch_bounds__(256) void csr_window_kernel(
    const u32* __restrict__ pairs, const u32* __restrict__ bcur,
    const u32* __restrict__ wbase,
    u32* __restrict__ rowS, u32* __restrict__ deg, int* __restrict__ srcS,
    int n, int wsz, int cap)
{
    __shared__ u32 dw[512];
    __shared__ u32 cw[512];
    __shared__ u32 ts[256];
    int grp = blockIdx.x;
    int t = threadIdx.x;
    int wlo = grp * wsz;
    int wnodes = n - wlo; if (wnodes < 0) wnodes = 0; if (wnodes > wsz) wnodes = wsz;
    u32 cnt = bcur[grp]; if (cnt > (u32)cap) cnt = (u32)cap;
    size_t base = (size_t)grp * cap;

    dw[t] = 0; dw[t + 256] = 0;
    __syncthreads();
    for (u32 i = t; i < cnt; i += 256)
        atomicAdd(&dw[pairs[base + i] >> 17], 1u);
    __syncthreads();

    int i0 = 2 * t, i1 = 2 * t + 1;
    u32 e0 = (i0 < wnodes) ? dw[i0] + 1u : 0u;
    u32 e1 = (i1 < wnodes) ? dw[i1] + 1u : 0u;
    ts[t] = e0 + e1;
    __syncthreads();
    for (int o = 1; o < 256; o <<= 1) {
        u32 y = (t >= o) ? ts[t - o] : 0u;
        __syncthreads();
        ts[t] += y;
        __syncthreads();
    }
    u32 off = wbase[grp] + ts[t] - (e0 + e1);   // exclusive
    if (i0 < wnodes) {
        u32 dgi = dw[i0];
        cw[i0] = off;
        rowS[wlo + i0] = off;
        deg[wlo + i0] = dgi;
        srcS[off + dgi] = wlo + i0;      // self-loop at last slot
    }
    u32 off1 = off + e0;
    if (i1 < wnodes) {
        u32 dgi = dw[i1];
        cw[i1] = off1;
        rowS[wlo + i1] = off1;
        deg[wlo + i1] = dgi;
        srcS[off1 + dgi] = wlo + i1;
    }
    __syncthreads();

    for (u32 i = t; i < cnt; i += 256) {
        u32 pr = pairs[base + i];
        u32 pos = atomicAdd(&cw[pr >> 17], 1u);
        srcS[pos] = (int)(pr & 0x1FFFFu);
    }
}

// ---------------- layer-1 fused softmax+aggregate (no-max softmax) ---------
// R3 structure; gathers now fp16 rows (8B per lane-quad).
__global__ __launch_bounds__(256) void l1_fused_kernel(
    const u32* __restrict__ rowS, const u32* __restrict__ deg,
    const int* __restrict__ srcS,
    const float* __restrict__ as_, const float* __restrict__ ad_,
    const u16* __restrict__ h16, const float* __restrict__ b1,
    float* __restrict__ h1r, int n)
{
    int d = (blockIdx.x * 256 + threadIdx.x) >> 6;
    int lane = threadIdx.x & 63;
    if (d >= n) return;
    int beg = (int)rowS[d];
    int end = beg + (int)deg[d] + 1;
    float adv = ad_[d];
    int e8 = lane >> 3;
    int q  = lane & 7;

    float sum = 0.f;
    float4 acc = make_float4(0.f, 0.f, 0.f, 0.f);
    for (int base = beg; base < end; base += 64) {
        int j = base + lane;
        bool valid = j < end;
        int s = valid ? srcS[j] : 0;
        float p = valid ? __expf(fminf(lrelu(as_[s] + adv), 60.f)) : 0.f;
        sum += p;                       // cross-lane reduce deferred to end
        int cnt = end - base; if (cnt > 64) cnt = 64;
        for (int jj = 0; jj < cnt; jj += 8) {
            int idx = jj + e8;
            int sj   = __shfl(s, idx, 64);
            float w  = __shfl(p, idx, 64);
            if (idx >= cnt) w = 0.f;    // convergent kill, row 0 broadcast
            float4 hv = ldq_h16(h16 + (size_t)sj * 32, q);
            acc.x += w * hv.x; acc.y += w * hv.y;
            acc.z += w * hv.z; acc.w += w * hv.w;
        }
    }
    for (int o = 32; o > 0; o >>= 1) sum += __shfl_xor(sum, o, 64);
    for (int o = 8; o < 64; o <<= 1) {
        acc.x += __shfl_xor(acc.x, o, 64);
        acc.y += __shfl_xor(acc.y, o, 64);
        acc.z += __shfl_xor(acc.z, o, 64);
        acc.w += __shfl_xor(acc.w, o, 64);
    }
    if (lane < 8) {
        float inv = 1.f / sum;
        float4 r;
        r.x = fmaxf(acc.x * inv + b1[4 * lane + 0], 0.f);
        r.y = fmaxf(acc.y * inv + b1[4 * lane + 1], 0.f);
        r.z = fmaxf(acc.z * inv + b1[4 * lane + 2], 0.f);
        r.w = fmaxf(acc.w * inv + b1[4 * lane + 3], 0.f);
        *(float4*)&h1r[(size_t)d * 32 + 4 * lane] = r;
    }
}

// ---------------- GEMM2: h1r @ {W_mu, W_ls} -> fp16 interleaved hmhl16 -----
// hmhl16 row = [mu 0..15 | ls 0..15] halves = one 64B line.
__global__ __launch_bounds__(256) void gemm2_kernel(
    const float* __restrict__ h1r,
    const float* __restrict__ Wm, const float* __restrict__ Wl_,
    const float* __restrict__ ams, const float* __restrict__ amd,
    const float* __restrict__ alsb, const float* __restrict__ ald,
    u16* __restrict__ hmhl16, float2* __restrict__ attn2,
    float* __restrict__ amud, float* __restrict__ alsd, int n)
{
    __shared__ float hs[16][33];
    __shared__ float Wms[32][16], Wls[32][16];
    __shared__ float amsv[16], amdv[16], alsv[16], aldv[16];
    int t = threadIdx.x;
    int rb = blockIdx.x * 16;

    for (int i = t; i < 512; i += 256) {
        int k = i >> 4, c = i & 15;
        Wms[k][c] = Wm[i];
        Wls[k][c] = Wl_[i];
    }
    if (t < 16) {
        amsv[t] = ams[t]; amdv[t] = amd[t];
        alsv[t] = alsb[t]; aldv[t] = ald[t];
    }
    for (int i = t; i < 512; i += 256) {
        int r = i >> 5, k = i & 31;
        int gr = rb + r;
        hs[r][k] = (gr < n) ? h1r[(size_t)gr * 32 + k] : 0.f;
    }
    __syncthreads();

    int tr = t >> 4;
    int c = t & 15;
    float accm = 0.f, accl = 0.f;
#pragma unroll
    for (int k = 0; k < 32; k++) {
        float hv = hs[tr][k];
        accm += hv * Wms[k][c];
        accl += hv * Wls[k][c];
    }
    int r = rb + tr;
    if (r < n) {
        hmhl16[(size_t)r * 32 + c]      = __half_as_ushort(__float2half(accm));
        hmhl16[(size_t)r * 32 + 16 + c] = __half_as_ushort(__float2half(accl));
    }
    float pms = accm * amsv[c], pmd = accm * amdv[c];
    float pls = accl * alsv[c], pld = accl * aldv[c];
    for (int m = 1; m < 16; m <<= 1) {
        pms += __shfl_xor(pms, m, 64);
        pmd += __shfl_xor(pmd, m, 64);
        pls += __shfl_xor(pls, m, 64);
        pld += __shfl_xor(pld, m, 64);
    }
    if (c == 0 && r < n) {
        attn2[r] = make_float2(pms, pls);
        amud[r] = pmd;
        alsd[r] = pld;
    }
}

// ---------------- layer-2 fused (mu & ls, no-max) + bias -> out -------------
// R3 structure; fp16 gathered rows (q<4 -> mu quad, q>=4 -> ls quad).
__global__ __launch_bounds__(256) void l2_fused_kernel(
    const u32* __restrict__ rowS, const u32* __restrict__ deg,
    const int* __restrict__ srcS,
    const float2* __restrict__ attn2,
    const float* __restrict__ amud, const float* __restrict__ alsd,
    const u16* __restrict__ hmhl16,
    const float* __restrict__ bm, const float* __restrict__ bl,
    float* __restrict__ out, int n)
{
    int d = (blockIdx.x * 256 + threadIdx.x) >> 6;
    int lane = threadIdx.x & 63;
    if (d >= n) return;
    int beg = (int)rowS[d];
    int end = beg + (int)deg[d] + 1;
    float amdv = amud[d], aldv = alsd[d];
    int e8 = lane >> 3;
    int q  = lane & 7;
    bool isMu = q < 4;

    float s_m = 0.f, s_l = 0.f;
    float4 acc = make_float4(0.f, 0.f, 0.f, 0.f);

    for (int base = beg; base < end; base += 64) {
        int j = base + lane;
        bool valid = j < end;
        int s = valid ? srcS[j] : 0;
        float2 a2 = valid ? attn2[s] : make_float2(0.f, 0.f);
        float pm = valid ? __expf(fminf(lrelu(a2.x + amdv), 60.f)) : 0.f;
        float pl = valid ? __expf(fminf(lrelu(a2.y + aldv), 60.f)) : 0.f;
        s_m += pm;
        s_l += pl;
        int cnt = end - base; if (cnt > 64) cnt = 64;
        for (int jj = 0; jj < cnt; jj += 8) {
            int idx = jj + e8;
            int sj    = __shfl(s, idx, 64);
            float pmj = __shfl(pm, idx, 64);
            float plj = __shfl(pl, idx, 64);
            float w = isMu ? pmj : plj;
            if (idx >= cnt) w = 0.f;
            float4 hv = ldq_h16(hmhl16 + (size_t)sj * 32, q);
            acc.x += w * hv.x; acc.y += w * hv.y;
            acc.z += w * hv.z; acc.w += w * hv.w;
        }
    }
    for (int o = 32; o > 0; o >>= 1) {
        s_m += __shfl_xor(s_m, o, 64);
        s_l += __shfl_xor(s_l, o, 64);
    }
    for (int o = 8; o < 64; o <<= 1) {
        acc.x += __shfl_xor(acc.x, o, 64);
        acc.y += __shfl_xor(acc.y, o, 64);
        acc.z += __shfl_xor(acc.z, o, 64);
        acc.w += __shfl_xor(acc.w, o, 64);
    }
    if (lane < 8) {
        if (lane < 4) {
            float inv = 1.f / s_m;
            float4 r;
            r.x = acc.x * inv + bm[4 * lane + 0];
            r.y = acc.y * inv + bm[4 * lane + 1];
            r.z = acc.z * inv + bm[4 * lane + 2];
            r.w = acc.w * inv + bm[4 * lane + 3];
            *(float4*)&out[(size_t)d * 16 + 4 * lane] = r;
        } else {
            float inv = 1.f / s_l;
            int qc = 4 * (lane - 4);
            float4 r;
            r.x = acc.x * inv + bl[qc + 0];
            r.y = acc.y * inv + bl[qc + 1];
            r.z = acc.z * inv + bl[qc + 2];
            r.w = acc.w * inv + bl[qc + 3];
            *(float4*)&out[(size_t)n * 16 + (size_t)d * 16 + qc] = r;
        }
    }
}

extern "C" void kernel_launch(void* const* d_in, const int* in_sizes, int n_in,
                              void* d_out, int out_size, void* d_ws, size_t ws_size,
                              hipStream_t stream)
{
    const float* x   = (const float*)d_in[0];
    const int*   ei  = (const int*)d_in[1];
    const float* W1  = (const float*)d_in[2];
    const float* a1s = (const float*)d_in[3];
    const float* a1d = (const float*)d_in[4];
    const float* b1  = (const float*)d_in[5];
    const float* Wm  = (const float*)d_in[6];
    const float* ams = (const float*)d_in[7];
    const float* amd = (const float*)d_in[8];
    const float* bm  = (const float*)d_in[9];
    const float* Wl  = (const float*)d_in[10];
    const float* als = (const float*)d_in[11];
    const float* ald = (const float*)d_in[12];
    const float* bl  = (const float*)d_in[13];

    int n  = in_sizes[0] / 128;
    int E  = in_sizes[1] / 2;
    int Et = E + n;
    int wsz = (n + NW - 1) / NW;          // 391 for n=100000 (fits 9 bits, <=512)
    int cap = E / NW + 3072;              // 39-sigma slack
    const int* srcI = ei;
    const int* dstI = ei + E;

    float* ws = (float*)d_ws;
    // Layout (floats), peak ~ 71n + Et + 600 ≈ 35.5 MB:
    //  [0,16n)    h16 (fp16, n x 32 halves) — gemm1 out, l1 gather table
    //  [16n,32n)  hmhl16 (fp16, [mu16|ls16]) — gemm2 out, l2 gather table
    //  [32n,64n)  h1r fp32 (l1 out, gemm2 in), ALIASED with pairs (9.5MB) before l1
    //  [64n,66n)  as_,ad_  -> attn2 (float2) after l1
    //  [66n,67n)  amud ; [67n,68n) alsd
    //  [68n,69n)  deg | [69n,69n+NW) bcur | [70n,71n) rowS
    //  [71n,71n+Et) srcS ; then wbase(256)
    u16*    h16   = (u16*)ws;
    u16*    hmhl16 = (u16*)(ws + (size_t)16 * n);
    float*  h1r  = ws + (size_t)32 * n;
    u32*    pairs = (u32*)(ws + (size_t)32 * n);
    float*  as_  = ws + (size_t)64 * n;
    float*  ad_  = ws + (size_t)65 * n;
    float2* attn2 = (float2*)(ws + (size_t)64 * n);
    float*  amud = ws + (size_t)66 * n;
    float*  alsd = ws + (size_t)67 * n;
    u32*    deg  = (u32*)(ws + (size_t)68 * n);
    u32*    bcur = (u32*)(ws + (size_t)69 * n);
    u32*    rowS = (u32*)(ws + (size_t)70 * n);
    int*    srcS = (int*)(ws + (size_t)71 * n);
    u32*    wbase = (u32*)(ws + (size_t)71 * n + Et);

    int pgrid = (E + PCHUNK - 1) / PCHUNK;

    hipMemsetAsync(bcur, 0, NW * sizeof(u32), stream);

    gemm1_kernel<<<(n + 63) / 64, 256, 0, stream>>>(x, W1, a1s, a1d, h16, as_, ad_, n);

    partition_kernel<<<pgrid, 256, 0, stream>>>(srcI, dstI, pairs, bcur, E, wsz, cap);
    wbase_kernel<<<1, NW, 0, stream>>>(bcur, wbase, n, wsz, cap);
    csr_window_kernel<<<NW, 256, 0, stream>>>(pairs, bcur, wbase,
                                              rowS, deg, srcS, n, wsz, cap);

    l1_fused_kernel<<<(n + 3) / 4, 256, 0, stream>>>(rowS, deg, srcS, as_, ad_,
                                                     h16, b1, h1r, n);

    gemm2_kernel<<<(n + 15) / 16, 256, 0, stream>>>(h1r, Wm, Wl, ams, amd, als, ald,
                                                    hmhl16, attn2, amud, alsd, n);

    l2_fused_kernel<<<(n + 3) / 4, 256, 0, stream>>>(rowS, deg, srcS,
                                                     attn2, amud, alsd,
                                                     hmhl16, bm, bl,
                                                     (float*)d_out, n);
}

// Round 7
// 263.437 us; speedup vs baseline: 1.2576x; 1.1149x over previous
//
#include <hip/hip_runtime.h>
#include <hip/hip_bf16.h>
#include <hip/hip_fp16.h>

typedef unsigned int u32;
typedef unsigned short u16;

__device__ __forceinline__ float lrelu(float v) {
    return v > 0.f ? v : 0.2f * v;
}

// load quad q (4 halves = 8B) of a 32-half row, convert to float4
__device__ __forceinline__ float4 ldq_h16(const u16* __restrict__ row, int q) {
    uint2 u = ((const uint2*)row)[q];
    __half2 a = *(__half2*)&u.x;
    __half2 b = *(__half2*)&u.y;
    float2 fa = __half22float2(a);
    float2 fb = __half22float2(b);
    return make_float4(fa.x, fa.y, fb.x, fb.y);
}

__device__ __forceinline__ u32 pack2h(float x, float y) {
    __half2 h = __float22half2_rn(make_float2(x, y));
    return *(u32*)&h;
}

// ---------------- GEMM1: h16 = fp16(x @ W1)  [n,128]x[128,32], + row dots --
__global__ __launch_bounds__(256) void gemm1_kernel(
    const float* __restrict__ x, const float* __restrict__ W,
    const float* __restrict__ a_src, const float* __restrict__ a_dst,
    u16* __restrict__ h16, float* __restrict__ as_, float* __restrict__ ad_,
    int n)
{
    __shared__ float xs[64][132];
    __shared__ float Wl[128][32];
    __shared__ float asv[32], adv[32];
    int t = threadIdx.x;
    int rb = blockIdx.x * 64;

    for (int i = t; i < 4096; i += 256) Wl[i >> 5][i & 31] = W[i];
    if (t < 32) { asv[t] = a_src[t]; adv[t] = a_dst[t]; }
    for (int i = t; i < 2048; i += 256) {
        int row = i >> 5, seg = i & 31;
        float4 v = make_float4(0.f, 0.f, 0.f, 0.f);
        if (rb + row < n)
            v = ((const float4*)(x + (size_t)(rb + row) * 128))[seg];
        int c = seg * 4;
        xs[row][c + 0] = v.x; xs[row][c + 1] = v.y;
        xs[row][c + 2] = v.z; xs[row][c + 3] = v.w;
    }
    __syncthreads();

    int tr = t >> 3;
    int tc = t & 7;
    float acc[2][4];
#pragma unroll
    for (int i = 0; i < 2; i++)
#pragma unroll
        for (int j = 0; j < 4; j++) acc[i][j] = 0.f;

#pragma unroll 4
    for (int k = 0; k < 128; k++) {
        float x0 = xs[tr][k];
        float x1 = xs[tr + 32][k];
        float4 wv = *(const float4*)&Wl[k][tc * 4];
        acc[0][0] += x0 * wv.x; acc[0][1] += x0 * wv.y;
        acc[0][2] += x0 * wv.z; acc[0][3] += x0 * wv.w;
        acc[1][0] += x1 * wv.x; acc[1][1] += x1 * wv.y;
        acc[1][2] += x1 * wv.z; acc[1][3] += x1 * wv.w;
    }

#pragma unroll
    for (int i = 0; i < 2; i++) {
        int r = rb + tr + i * 32;
        if (r < n) {
            uint2 p;
            p.x = pack2h(acc[i][0], acc[i][1]);
            p.y = pack2h(acc[i][2], acc[i][3]);
            *(uint2*)&h16[(size_t)r * 32 + tc * 4] = p;
        }
        float ps = 0.f, pd = 0.f;
#pragma unroll
        for (int j = 0; j < 4; j++) {
            int c = tc * 4 + j;
            ps += acc[i][j] * asv[c];
            pd += acc[i][j] * adv[c];
        }
        for (int m = 1; m < 8; m <<= 1) {
            ps += __shfl_xor(ps, m, 64);
            pd += __shfl_xor(pd, m, 64);
        }
        if (tc == 0 && r < n) { as_[r] = ps; ad_[r] = pd; }
    }
}

// ---------------- CSR build (partition-first, zero device atomics) --------
// pairs packed u32: (d - window_base) << 17 | src  (src<2^17, dloc<2^9)
#define PCHUNK 4096
#define NW 256
__global__ __launch_bounds__(256) void partition_kernel(
    const int* __restrict__ srcI, const int* __restrict__ dstI,
    u32* __restrict__ pairs, u32* __restrict__ bcur,
    int E, int wsz, int cap)
{
    __shared__ u32 lcount[NW];
    __shared__ u32 lbase[NW];
    int t = threadIdx.x;
    for (int chunk = blockIdx.x * PCHUNK; chunk < E; chunk += gridDim.x * PCHUNK) {
        lcount[t] = 0;
        __syncthreads();
        u32 pk[16]; int wv[16]; u32 rk[16]; bool val[16];
#pragma unroll
        for (int k = 0; k < 16; k++) {
            int i = chunk + k * 256 + t;
            val[k] = i < E;
            if (val[k]) {
                u32 s = (u32)srcI[i];
                u32 d = (u32)dstI[i];
                wv[k] = d / (u32)wsz;
                u32 dloc = d - (u32)wv[k] * (u32)wsz;
                pk[k] = (dloc << 17) | s;
                rk[k] = atomicAdd(&lcount[wv[k]], 1u);
            }
        }
        __syncthreads();
        if (lcount[t] > 0)
            lbase[t] = atomicAdd(&bcur[t], lcount[t]);
        __syncthreads();
#pragma unroll
        for (int k = 0; k < 16; k++) {
            if (val[k]) {
                u32 pos = lbase[wv[k]] + rk[k];
                if (pos < (u32)cap)   // overflow guard (P ~ 0, 39 sigma)
                    pairs[(size_t)wv[k] * cap + pos] = pk[k];
            }
        }
        __syncthreads();
    }
}

// window totals -> exclusive window bases. total(g) = min(bcur,cap) + wnodes
__global__ void wbase_kernel(const u32* __restrict__ bcur,
                             u32* __restrict__ wbase, int n, int wsz, int cap)
{
    __shared__ u32 ts[NW];
    int t = threadIdx.x;
    int wlo = t * wsz;
    int wnodes = n - wlo; if (wnodes < 0) wnodes = 0; if (wnodes > wsz) wnodes = wsz;
    u32 cnt = bcur[t]; if (cnt > (u32)cap) cnt = (u32)cap;
    u32 tot = cnt + (u32)wnodes;
    ts[t] = tot; __syncthreads();
    for (int o = 1; o < NW; o <<= 1) {
        u32 y = (t >= o) ? ts[t - o] : 0u;
        __syncthreads();
        ts[t] += y;
        __syncthreads();
    }
    wbase[t] = ts[t] - tot;   // exclusive
}

// Fused CSR epilogue: hist -> local scan -> rowS/deg/self-loop -> scatter.
__global__ __launch_bounds__(256) void csr_window_kernel(
    const u32* __restrict__ pairs, const u32* __restrict__ bcur,
    const u32* __restrict__ wbase,
    u32* __restrict__ rowS, u32* __restrict__ deg, int* __restrict__ srcS,
    int n, int wsz, int cap)
{
    __shared__ u32 dw[512];
    __shared__ u32 cw[512];
    __shared__ u32 ts[256];
    int grp = blockIdx.x;
    int t = threadIdx.x;
    int wlo = grp * wsz;
    int wnodes = n - wlo; if (wnodes < 0) wnodes = 0; if (wnodes > wsz) wnodes = wsz;
    u32 cnt = bcur[grp]; if (cnt > (u32)cap) cnt = (u32)cap;
    size_t base = (size_t)grp * cap;

    dw[t] = 0; dw[t + 256] = 0;
    __syncthreads();
    for (u32 i = t; i < cnt; i += 256)
        atomicAdd(&dw[pairs[base + i] >> 17], 1u);
    __syncthreads();

    int i0 = 2 * t, i1 = 2 * t + 1;
    u32 e0 = (i0 < wnodes) ? dw[i0] + 1u : 0u;
    u32 e1 = (i1 < wnodes) ? dw[i1] + 1u : 0u;
    ts[t] = e0 + e1;
    __syncthreads();
    for (int o = 1; o < 256; o <<= 1) {
        u32 y = (t >= o) ? ts[t - o] : 0u;
        __syncthreads();
        ts[t] += y;
        __syncthreads();
    }
    u32 off = wbase[grp] + ts[t] - (e0 + e1);   // exclusive
    if (i0 < wnodes) {
        u32 dgi = dw[i0];
        cw[i0] = off;
        rowS[wlo + i0] = off;
        deg[wlo + i0] = dgi;
        srcS[off + dgi] = wlo + i0;      // self-loop at last slot
    }
    u32 off1 = off + e0;
    if (i1 < wnodes) {
        u32 dgi = dw[i1];
        cw[i1] = off1;
        rowS[wlo + i1] = off1;
        deg[wlo + i1] = dgi;
        srcS[off1 + dgi] = wlo + i1;
    }
    __syncthreads();

    for (u32 i = t; i < cnt; i += 256) {
        u32 pr = pairs[base + i];
        u32 pos = atomicAdd(&cw[pr >> 17], 1u);
        srcS[pos] = (int)(pr & 0x1FFFFu);
    }
}

// ---------------- layer-1 fused (quarter-wave: 1 dst per 16 lanes) ---------
// lane = e2*8 + q within group: 2 edges in flight x 8 quads. Edge phase:
// 16-edge tile, one edge per lane. Inner: group-local shuffles distribute
// (s,p); each lane accumulates w into wsum -> the e2-fold (one shfl_xor(8))
// produces BOTH the softmax sum and the acc in output position. Tail chain
// depth ~2 vs 9 in the 64-lane version; 4 dsts per wave.
__global__ __launch_bounds__(256) void l1_fused_kernel(
    const u32* __restrict__ rowS, const u32* __restrict__ deg,
    const int* __restrict__ srcS,
    const float* __restrict__ as_, const float* __restrict__ ad_,
    const u16* __restrict__ h16, const float* __restrict__ b1,
    float* __restrict__ h1r, int n)
{
    int d = blockIdx.x * 16 + (threadIdx.x >> 4);
    if (d >= n) return;
    int l  = threadIdx.x & 15;           // lane in group
    int e2 = l >> 3;                     // 0/1: edge parity in flight
    int q  = l & 7;                      // quad (4 floats) of the 32-ch row
    int gb = (threadIdx.x & 63) & 48;    // group base lane within wave

    int beg = (int)rowS[d];
    int end = beg + (int)deg[d] + 1;
    float adv = ad_[d];

    float wsum = 0.f;
    float4 acc = make_float4(0.f, 0.f, 0.f, 0.f);

    for (int tb = beg; tb < end; tb += 16) {
        int j = tb + l;
        bool valid = j < end;
        int s = valid ? srcS[j] : 0;
        float p = valid ? __expf(fminf(lrelu(as_[s] + adv), 60.f)) : 0.f;
        int cnt = end - tb; if (cnt > 16) cnt = 16;
        for (int jj = 0; jj < cnt; jj += 2) {
            int idx = jj + e2;
            int sj  = __shfl(s, gb + idx, 64);
            float w = __shfl(p, gb + idx, 64);
            if (idx >= cnt) w = 0.f;     // convergent kill (row 0 broadcast)
            wsum += w;
            float4 hv = ldq_h16(h16 + (size_t)sj * 32, q);
            acc.x += w * hv.x; acc.y += w * hv.y;
            acc.z += w * hv.z; acc.w += w * hv.w;
        }
    }
    // single e2-fold: lane l pairs with l^8 (same q, other parity)
    wsum  += __shfl_xor(wsum, 8, 64);
    acc.x += __shfl_xor(acc.x, 8, 64);
    acc.y += __shfl_xor(acc.y, 8, 64);
    acc.z += __shfl_xor(acc.z, 8, 64);
    acc.w += __shfl_xor(acc.w, 8, 64);
    if (l < 8) {
        float inv = 1.f / wsum;
        float4 r;
        r.x = fmaxf(acc.x * inv + b1[4 * q + 0], 0.f);
        r.y = fmaxf(acc.y * inv + b1[4 * q + 1], 0.f);
        r.z = fmaxf(acc.z * inv + b1[4 * q + 2], 0.f);
        r.w = fmaxf(acc.w * inv + b1[4 * q + 3], 0.f);
        *(float4*)&h1r[(size_t)d * 32 + 4 * q] = r;
    }
}

// ---------------- GEMM2: h1r @ {W_mu, W_ls} -> fp16 interleaved hmhl16 -----
__global__ __launch_bounds__(256) void gemm2_kernel(
    const float* __restrict__ h1r,
    const float* __restrict__ Wm, const float* __restrict__ Wl_,
    const float* __restrict__ ams, const float* __restrict__ amd,
    const float* __restrict__ alsb, const float* __restrict__ ald,
    u16* __restrict__ hmhl16, float2* __restrict__ attn2,
    float* __restrict__ amud, float* __restrict__ alsd, int n)
{
    __shared__ float hs[16][33];
    __shared__ float Wms[32][16], Wls[32][16];
    __shared__ float amsv[16], amdv[16], alsv[16], aldv[16];
    int t = threadIdx.x;
    int rb = blockIdx.x * 16;

    for (int i = t; i < 512; i += 256) {
        int k = i >> 4, c = i & 15;
        Wms[k][c] = Wm[i];
        Wls[k][c] = Wl_[i];
    }
    if (t < 16) {
        amsv[t] = ams[t]; amdv[t] = amd[t];
        alsv[t] = alsb[t]; aldv[t] = ald[t];
    }
    for (int i = t; i < 512; i += 256) {
        int r = i >> 5, k = i & 31;
        int gr = rb + r;
        hs[r][k] = (gr < n) ? h1r[(size_t)gr * 32 + k] : 0.f;
    }
    __syncthreads();

    int tr = t >> 4;
    int c = t & 15;
    float accm = 0.f, accl = 0.f;
#pragma unroll
    for (int k = 0; k < 32; k++) {
        float hv = hs[tr][k];
        accm += hv * Wms[k][c];
        accl += hv * Wls[k][c];
    }
    int r = rb + tr;
    if (r < n) {
        hmhl16[(size_t)r * 32 + c]      = __half_as_ushort(__float2half(accm));
        hmhl16[(size_t)r * 32 + 16 + c] = __half_as_ushort(__float2half(accl));
    }
    float pms = accm * amsv[c], pmd = accm * amdv[c];
    float pls = accl * alsv[c], pld = accl * aldv[c];
    for (int m = 1; m < 16; m <<= 1) {
        pms += __shfl_xor(pms, m, 64);
        pmd += __shfl_xor(pmd, m, 64);
        pls += __shfl_xor(pls, m, 64);
        pld += __shfl_xor(pld, m, 64);
    }
    if (c == 0 && r < n) {
        attn2[r] = make_float2(pms, pls);
        amud[r] = pmd;
        alsd[r] = pld;
    }
}

// ---------------- layer-2 fused (quarter-wave, mu & ls) --------------------
// q<4 -> mu quad 4q, q>=4 -> ls quad 4(q-4); row hmhl16[s] = [mu16|ls16] so
// quad index q covers both halves. Per-lane wsum accumulates the selected
// weight -> after the e2-fold, q<4 lanes hold s_m and q>=4 lanes hold s_l,
// exactly where the output quad lives. Zero-shuffle epilogue.
__global__ __launch_bounds__(256) void l2_fused_kernel(
    const u32* __restrict__ rowS, const u32* __restrict__ deg,
    const int* __restrict__ srcS,
    const float2* __restrict__ attn2,
    const float* __restrict__ amud, const float* __restrict__ alsd,
    const u16* __restrict__ hmhl16,
    const float* __restrict__ bm, const float* __restrict__ bl,
    float* __restrict__ out, int n)
{
    int d = blockIdx.x * 16 + (threadIdx.x >> 4);
    if (d >= n) return;
    int l  = threadIdx.x & 15;
    int e2 = l >> 3;
    int q  = l & 7;
    int gb = (threadIdx.x & 63) & 48;
    bool isMu = q < 4;

    int beg = (int)rowS[d];
    int end = beg + (int)deg[d] + 1;
    float amdv = amud[d], aldv = alsd[d];

    float wsum = 0.f;
    float4 acc = make_float4(0.f, 0.f, 0.f, 0.f);

    for (int tb = beg; tb < end; tb += 16) {
        int j = tb + l;
        bool valid = j < end;
        int s = valid ? srcS[j] : 0;
        float2 a2 = valid ? attn2[s] : make_float2(0.f, 0.f);
        float pm = valid ? __expf(fminf(lrelu(a2.x + amdv), 60.f)) : 0.f;
        float pl = valid ? __expf(fminf(lrelu(a2.y + aldv), 60.f)) : 0.f;
        int cnt = end - tb; if (cnt > 16) cnt = 16;
        for (int jj = 0; jj < cnt; jj += 2) {
            int idx = jj + e2;
            int sj    = __shfl(s, gb + idx, 64);
            float pmj = __shfl(pm, gb + idx, 64);
            float plj = __shfl(pl, gb + idx, 64);
            float w = isMu ? pmj : plj;
            if (idx >= cnt) w = 0.f;
            wsum += w;
            float4 hv = ldq_h16(hmhl16 + (size_t)sj * 32, q);
            acc.x += w * hv.x; acc.y += w * hv.y;
            acc.z += w * hv.z; acc.w += w * hv.w;
        }
    }
    wsum  += __shfl_xor(wsum, 8, 64);    // same q, other parity
    acc.x += __shfl_xor(acc.x, 8, 64);
    acc.y += __shfl_xor(acc.y, 8, 64);
    acc.z += __shfl_xor(acc.z, 8, 64);
    acc.w += __shfl_xor(acc.w, 8, 64);
    if (l < 8) {
        float inv = 1.f / wsum;          // s_m for q<4, s_l for q>=4
        if (q < 4) {
            float4 r;
            r.x = acc.x * inv + bm[4 * q + 0];
            r.y = acc.y * inv + bm[4 * q + 1];
            r.z = acc.z * inv + bm[4 * q + 2];
            r.w = acc.w * inv + bm[4 * q + 3];
            *(float4*)&out[(size_t)d * 16 + 4 * q] = r;
        } else {
            int qc = 4 * (q - 4);
            float4 r;
            r.x = acc.x * inv + bl[qc + 0];
            r.y = acc.y * inv + bl[qc + 1];
            r.z = acc.z * inv + bl[qc + 2];
            r.w = acc.w * inv + bl[qc + 3];
            *(float4*)&out[(size_t)n * 16 + (size_t)d * 16 + qc] = r;
        }
    }
}

extern "C" void kernel_launch(void* const* d_in, const int* in_sizes, int n_in,
                              void* d_out, int out_size, void* d_ws, size_t ws_size,
                              hipStream_t stream)
{
    const float* x   = (const float*)d_in[0];
    const int*   ei  = (const int*)d_in[1];
    const float* W1  = (const float*)d_in[2];
    const float* a1s = (const float*)d_in[3];
    const float* a1d = (const float*)d_in[4];
    const float* b1  = (const float*)d_in[5];
    const float* Wm  = (const float*)d_in[6];
    const float* ams = (const float*)d_in[7];
    const float* amd = (const float*)d_in[8];
    const float* bm  = (const float*)d_in[9];
    const float* Wl  = (const float*)d_in[10];
    const float* als = (const float*)d_in[11];
    const float* ald = (const float*)d_in[12];
    const float* bl  = (const float*)d_in[13];

    int n  = in_sizes[0] / 128;
    int E  = in_sizes[1] / 2;
    int Et = E + n;
    int wsz = (n + NW - 1) / NW;          // 391 for n=100000 (fits 9 bits, <=512)
    int cap = E / NW + 3072;              // 39-sigma slack
    const int* srcI = ei;
    const int* dstI = ei + E;

    float* ws = (float*)d_ws;
    // Layout (floats), peak ~ 71n + Et + 600 ≈ 35.5 MB:
    //  [0,16n)    h16 (fp16, n x 32 halves) — gemm1 out, l1 gather table
    //  [16n,32n)  hmhl16 (fp16, [mu16|ls16]) — gemm2 out, l2 gather table
    //  [32n,64n)  h1r fp32 (l1 out, gemm2 in), ALIASED with pairs (9.5MB) before l1
    //  [64n,66n)  as_,ad_  -> attn2 (float2) after l1
    //  [66n,67n)  amud ; [67n,68n) alsd
    //  [68n,69n)  deg | [69n,69n+NW) bcur | [70n,71n) rowS
    //  [71n,71n+Et) srcS ; then wbase(256)
    u16*    h16   = (u16*)ws;
    u16*    hmhl16 = (u16*)(ws + (size_t)16 * n);
    float*  h1r  = ws + (size_t)32 * n;
    u32*    pairs = (u32*)(ws + (size_t)32 * n);
    float*  as_  = ws + (size_t)64 * n;
    float*  ad_  = ws + (size_t)65 * n;
    float2* attn2 = (float2*)(ws + (size_t)64 * n);
    float*  amud = ws + (size_t)66 * n;
    float*  alsd = ws + (size_t)67 * n;
    u32*    deg  = (u32*)(ws + (size_t)68 * n);
    u32*    bcur = (u32*)(ws + (size_t)69 * n);
    u32*    rowS = (u32*)(ws + (size_t)70 * n);
    int*    srcS = (int*)(ws + (size_t)71 * n);
    u32*    wbase = (u32*)(ws + (size_t)71 * n + Et);

    int pgrid = (E + PCHUNK - 1) / PCHUNK;

    hipMemsetAsync(bcur, 0, NW * sizeof(u32), stream);

    gemm1_kernel<<<(n + 63) / 64, 256, 0, stream>>>(x, W1, a1s, a1d, h16, as_, ad_, n);

    partition_kernel<<<pgrid, 256, 0, stream>>>(srcI, dstI, pairs, bcur, E, wsz, cap);
    wbase_kernel<<<1, NW, 0, stream>>>(bcur, wbase, n, wsz, cap);
    csr_window_kernel<<<NW, 256, 0, stream>>>(pairs, bcur, wbase,
                                              rowS, deg, srcS, n, wsz, cap);

    l1_fused_kernel<<<(n + 15) / 16, 256, 0, stream>>>(rowS, deg, srcS, as_, ad_,
                                                       h16, b1, h1r, n);

    gemm2_kernel<<<(n + 15) / 16, 256, 0, stream>>>(h1r, Wm, Wl, ams, amd, als, ald,
                                                    hmhl16, attn2, amud, alsd, n);

    l2_fused_kernel<<<(n + 15) / 16, 256, 0, stream>>>(rowS, deg, srcS,
                                                       attn2, amud, alsd,
                                                       hmhl16, bm, bl,
                                                       (float*)d_out, n);
}

// Round 8
// 257.033 us; speedup vs baseline: 1.2889x; 1.0249x over previous
//
#include <hip/hip_runtime.h>
#include <hip/hip_bf16.h>
#include <hip/hip_fp16.h>

typedef unsigned int u32;
typedef unsigned short u16;

__device__ __forceinline__ float lrelu(float v) {
    return v > 0.f ? v : 0.2f * v;
}

// load quad q (4 halves = 8B) of a 32-half row, convert to float4
__device__ __forceinline__ float4 ldq_h16(const u16* __restrict__ row, int q) {
    uint2 u = ((const uint2*)row)[q];
    __half2 a = *(__half2*)&u.x;
    __half2 b = *(__half2*)&u.y;
    float2 fa = __half22float2(a);
    float2 fb = __half22float2(b);
    return make_float4(fa.x, fa.y, fb.x, fb.y);
}

__device__ __forceinline__ u32 pack2h(float x, float y) {
    __half2 h = __float22half2_rn(make_float2(x, y));
    return *(u32*)&h;
}

#define PCHUNK 4096
#define NW 256

// ---------------- FAT: partition (blocks [0,pgrid)) ∥ gemm1 (rest) ---------
// The two are independent; partition is HBM-bound, gemm1 VALU-bound ->
// co-residency overlaps the pipes. Partition blocks dispatched first.
// pairs packed u32: (d - window_base) << 17 | src  (src<2^17, dloc<2^9)
__global__ __launch_bounds__(256) void g1p_kernel(
    const float* __restrict__ x, const float* __restrict__ W,
    const float* __restrict__ a_src, const float* __restrict__ a_dst,
    u16* __restrict__ h16, float* __restrict__ as_, float* __restrict__ ad_,
    const int* __restrict__ srcI, const int* __restrict__ dstI,
    u32* __restrict__ pairs, u32* __restrict__ bcur,
    int n, int E, int wsz, int cap, int pgrid)
{
    __shared__ float xs[64][132];
    __shared__ float Wl[128][32];
    __shared__ float asv[32], adv[32];
    __shared__ u32 lcount[NW];
    __shared__ u32 lbase[NW];
    int t = threadIdx.x;

    if ((int)blockIdx.x < pgrid) {
        // ---- partition body: one 4096-edge chunk per block ----
        int chunk = blockIdx.x * PCHUNK;
        lcount[t] = 0;
        __syncthreads();
        u32 pk[16]; int wv[16]; u32 rk[16]; bool val[16];
#pragma unroll
        for (int k = 0; k < 16; k++) {
            int i = chunk + k * 256 + t;
            val[k] = i < E;
            if (val[k]) {
                u32 s = (u32)srcI[i];
                u32 d = (u32)dstI[i];
                wv[k] = d / (u32)wsz;
                u32 dloc = d - (u32)wv[k] * (u32)wsz;
                pk[k] = (dloc << 17) | s;
                rk[k] = atomicAdd(&lcount[wv[k]], 1u);
            }
        }
        __syncthreads();
        if (lcount[t] > 0)
            lbase[t] = atomicAdd(&bcur[t], lcount[t]);
        __syncthreads();
#pragma unroll
        for (int k = 0; k < 16; k++) {
            if (val[k]) {
                u32 pos = lbase[wv[k]] + rk[k];
                if (pos < (u32)cap)   // overflow guard (P ~ 0, 39 sigma)
                    pairs[(size_t)wv[k] * cap + pos] = pk[k];
            }
        }
        return;
    }

    // ---- gemm1 body: h16 = fp16(x @ W1), + as_/ad_ row dots ----
    int rb = (blockIdx.x - pgrid) * 64;

    for (int i = t; i < 4096; i += 256) Wl[i >> 5][i & 31] = W[i];
    if (t < 32) { asv[t] = a_src[t]; adv[t] = a_dst[t]; }
    for (int i = t; i < 2048; i += 256) {
        int row = i >> 5, seg = i & 31;
        float4 v = make_float4(0.f, 0.f, 0.f, 0.f);
        if (rb + row < n)
            v = ((const float4*)(x + (size_t)(rb + row) * 128))[seg];
        int c = seg * 4;
        xs[row][c + 0] = v.x; xs[row][c + 1] = v.y;
        xs[row][c + 2] = v.z; xs[row][c + 3] = v.w;
    }
    __syncthreads();

    int tr = t >> 3;
    int tc = t & 7;
    float acc[2][4];
#pragma unroll
    for (int i = 0; i < 2; i++)
#pragma unroll
        for (int j = 0; j < 4; j++) acc[i][j] = 0.f;

#pragma unroll 4
    for (int k = 0; k < 128; k++) {
        float x0 = xs[tr][k];
        float x1 = xs[tr + 32][k];
        float4 wv = *(const float4*)&Wl[k][tc * 4];
        acc[0][0] += x0 * wv.x; acc[0][1] += x0 * wv.y;
        acc[0][2] += x0 * wv.z; acc[0][3] += x0 * wv.w;
        acc[1][0] += x1 * wv.x; acc[1][1] += x1 * wv.y;
        acc[1][2] += x1 * wv.z; acc[1][3] += x1 * wv.w;
    }

#pragma unroll
    for (int i = 0; i < 2; i++) {
        int r = rb + tr + i * 32;
        if (r < n) {
            uint2 p;
            p.x = pack2h(acc[i][0], acc[i][1]);
            p.y = pack2h(acc[i][2], acc[i][3]);
            *(uint2*)&h16[(size_t)r * 32 + tc * 4] = p;
        }
        float ps = 0.f, pd = 0.f;
#pragma unroll
        for (int j = 0; j < 4; j++) {
            int c = tc * 4 + j;
            ps += acc[i][j] * asv[c];
            pd += acc[i][j] * adv[c];
        }
        for (int m = 1; m < 8; m <<= 1) {
            ps += __shfl_xor(ps, m, 64);
            pd += __shfl_xor(pd, m, 64);
        }
        if (tc == 0 && r < n) { as_[r] = ps; ad_[r] = pd; }
    }
}

// Fused CSR epilogue (wbase folded in): every block computes the 256-wide
// prefix over bcur totals itself (cheap), then hist -> local scan ->
// rowS/deg/self-loop stores -> scatter. Zero device atomics.
__global__ __launch_bounds__(256) void csr_window_kernel(
    const u32* __restrict__ pairs, const u32* __restrict__ bcur,
    u32* __restrict__ rowS, u32* __restrict__ deg, int* __restrict__ srcS,
    int n, int wsz, int cap)
{
    __shared__ u32 dw[512];
    __shared__ u32 cw[512];
    __shared__ u32 ts[256];
    int grp = blockIdx.x;
    int t = threadIdx.x;
    int wlo = grp * wsz;
    int wnodes = n - wlo; if (wnodes < 0) wnodes = 0; if (wnodes > wsz) wnodes = wsz;
    u32 cnt = bcur[grp]; if (cnt > (u32)cap) cnt = (u32)cap;
    size_t base = (size_t)grp * cap;

    // ---- folded wbase: prefix over all groups' totals ----
    {
        int wlo_t = t * wsz;
        int wn_t = n - wlo_t; if (wn_t < 0) wn_t = 0; if (wn_t > wsz) wn_t = wsz;
        u32 c_t = bcur[t]; if (c_t > (u32)cap) c_t = (u32)cap;
        ts[t] = c_t + (u32)wn_t;
        __syncthreads();
        for (int o = 1; o < NW; o <<= 1) {
            u32 y = (t >= o) ? ts[t - o] : 0u;
            __syncthreads();
            ts[t] += y;
            __syncthreads();
        }
    }
    u32 wb = ts[grp] - (cnt + (u32)wnodes);   // exclusive base for this group
    __syncthreads();                           // ts reused below

    dw[t] = 0; dw[t + 256] = 0;
    __syncthreads();
    for (u32 i = t; i < cnt; i += 256)
        atomicAdd(&dw[pairs[base + i] >> 17], 1u);
    __syncthreads();

    int i0 = 2 * t, i1 = 2 * t + 1;
    u32 e0 = (i0 < wnodes) ? dw[i0] + 1u : 0u;
    u32 e1 = (i1 < wnodes) ? dw[i1] + 1u : 0u;
    ts[t] = e0 + e1;
    __syncthreads();
    for (int o = 1; o < 256; o <<= 1) {
        u32 y = (t >= o) ? ts[t - o] : 0u;
        __syncthreads();
        ts[t] += y;
        __syncthreads();
    }
    u32 off = wb + ts[t] - (e0 + e1);   // exclusive
    if (i0 < wnodes) {
        u32 dgi = dw[i0];
        cw[i0] = off;
        rowS[wlo + i0] = off;
        deg[wlo + i0] = dgi;
        srcS[off + dgi] = wlo + i0;      // self-loop at last slot
    }
    u32 off1 = off + e0;
    if (i1 < wnodes) {
        u32 dgi = dw[i1];
        cw[i1] = off1;
        rowS[wlo + i1] = off1;
        deg[wlo + i1] = dgi;
        srcS[off1 + dgi] = wlo + i1;
    }
    __syncthreads();

    for (u32 i = t; i < cnt; i += 256) {
        u32 pr = pairs[base + i];
        u32 pos = atomicAdd(&cw[pr >> 17], 1u);
        srcS[pos] = (int)(pr & 0x1FFFFu);
    }
}

// ---------------- layer-1 fused (quarter-wave: 1 dst per 16 lanes) ---------
__global__ __launch_bounds__(256) void l1_fused_kernel(
    const u32* __restrict__ rowS, const u32* __restrict__ deg,
    const int* __restrict__ srcS,
    const float* __restrict__ as_, const float* __restrict__ ad_,
    const u16* __restrict__ h16, const float* __restrict__ b1,
    float* __restrict__ h1r, int n)
{
    int d = blockIdx.x * 16 + (threadIdx.x >> 4);
    if (d >= n) return;
    int l  = threadIdx.x & 15;           // lane in group
    int e2 = l >> 3;                     // 0/1: edge parity in flight
    int q  = l & 7;                      // quad (4 floats) of the 32-ch row
    int gb = (threadIdx.x & 63) & 48;    // group base lane within wave

    int beg = (int)rowS[d];
    int end = beg + (int)deg[d] + 1;
    float adv = ad_[d];

    float wsum = 0.f;
    float4 acc = make_float4(0.f, 0.f, 0.f, 0.f);

    for (int tb = beg; tb < end; tb += 16) {
        int j = tb + l;
        bool valid = j < end;
        int s = valid ? srcS[j] : 0;
        float p = valid ? __expf(fminf(lrelu(as_[s] + adv), 60.f)) : 0.f;
        int cnt = end - tb; if (cnt > 16) cnt = 16;
        for (int jj = 0; jj < cnt; jj += 2) {
            int idx = jj + e2;
            int sj  = __shfl(s, gb + idx, 64);
            float w = __shfl(p, gb + idx, 64);
            if (idx >= cnt) w = 0.f;     // convergent kill (row 0 broadcast)
            wsum += w;
            float4 hv = ldq_h16(h16 + (size_t)sj * 32, q);
            acc.x += w * hv.x; acc.y += w * hv.y;
            acc.z += w * hv.z; acc.w += w * hv.w;
        }
    }
    // single e2-fold: lane l pairs with l^8 (same q, other parity)
    wsum  += __shfl_xor(wsum, 8, 64);
    acc.x += __shfl_xor(acc.x, 8, 64);
    acc.y += __shfl_xor(acc.y, 8, 64);
    acc.z += __shfl_xor(acc.z, 8, 64);
    acc.w += __shfl_xor(acc.w, 8, 64);
    if (l < 8) {
        float inv = 1.f / wsum;
        float4 r;
        r.x = fmaxf(acc.x * inv + b1[4 * q + 0], 0.f);
        r.y = fmaxf(acc.y * inv + b1[4 * q + 1], 0.f);
        r.z = fmaxf(acc.z * inv + b1[4 * q + 2], 0.f);
        r.w = fmaxf(acc.w * inv + b1[4 * q + 3], 0.f);
        *(float4*)&h1r[(size_t)d * 32 + 4 * q] = r;
    }
}

// ---------------- GEMM2: h1r @ {W_mu, W_ls} -> fp16 interleaved hmhl16 -----
__global__ __launch_bounds__(256) void gemm2_kernel(
    const float* __restrict__ h1r,
    const float* __restrict__ Wm, const float* __restrict__ Wl_,
    const float* __restrict__ ams, const float* __restrict__ amd,
    const float* __restrict__ alsb, const float* __restrict__ ald,
    u16* __restrict__ hmhl16, float2* __restrict__ attn2,
    float* __restrict__ amud, float* __restrict__ alsd, int n)
{
    __shared__ float hs[16][33];
    __shared__ float Wms[32][16], Wls[32][16];
    __shared__ float amsv[16], amdv[16], alsv[16], aldv[16];
    int t = threadIdx.x;
    int rb = blockIdx.x * 16;

    for (int i = t; i < 512; i += 256) {
        int k = i >> 4, c = i & 15;
        Wms[k][c] = Wm[i];
        Wls[k][c] = Wl_[i];
    }
    if (t < 16) {
        amsv[t] = ams[t]; amdv[t] = amd[t];
        alsv[t] = alsb[t]; aldv[t] = ald[t];
    }
    for (int i = t; i < 512; i += 256) {
        int r = i >> 5, k = i & 31;
        int gr = rb + r;
        hs[r][k] = (gr < n) ? h1r[(size_t)gr * 32 + k] : 0.f;
    }
    __syncthreads();

    int tr = t >> 4;
    int c = t & 15;
    float accm = 0.f, accl = 0.f;
#pragma unroll
    for (int k = 0; k < 32; k++) {
        float hv = hs[tr][k];
        accm += hv * Wms[k][c];
        accl += hv * Wls[k][c];
    }
    int r = rb + tr;
    if (r < n) {
        hmhl16[(size_t)r * 32 + c]      = __half_as_ushort(__float2half(accm));
        hmhl16[(size_t)r * 32 + 16 + c] = __half_as_ushort(__float2half(accl));
    }
    float pms = accm * amsv[c], pmd = accm * amdv[c];
    float pls = accl * alsv[c], pld = accl * aldv[c];
    for (int m = 1; m < 16; m <<= 1) {
        pms += __shfl_xor(pms, m, 64);
        pmd += __shfl_xor(pmd, m, 64);
        pls += __shfl_xor(pls, m, 64);
        pld += __shfl_xor(pld, m, 64);
    }
    if (c == 0 && r < n) {
        attn2[r] = make_float2(pms, pls);
        amud[r] = pmd;
        alsd[r] = pld;
    }
}

// ---------------- layer-2 fused (quarter-wave, mu & ls) --------------------
__global__ __launch_bounds__(256) void l2_fused_kernel(
    const u32* __restrict__ rowS, const u32* __restrict__ deg,
    const int* __restrict__ srcS,
    const float2* __restrict__ attn2,
    const float* __restrict__ amud, const float* __restrict__ alsd,
    const u16* __restrict__ hmhl16,
    const float* __restrict__ bm, const float* __restrict__ bl,
    float* __restrict__ out, int n)
{
    int d = blockIdx.x * 16 + (threadIdx.x >> 4);
    if (d >= n) return;
    int l  = threadIdx.x & 15;
    int e2 = l >> 3;
    int q  = l & 7;
    int gb = (threadIdx.x & 63) & 48;
    bool isMu = q < 4;

    int beg = (int)rowS[d];
    int end = beg + (int)deg[d] + 1;
    float amdv = amud[d], aldv = alsd[d];

    float wsum = 0.f;
    float4 acc = make_float4(0.f, 0.f, 0.f, 0.f);

    for (int tb = beg; tb < end; tb += 16) {
        int j = tb + l;
        bool valid = j < end;
        int s = valid ? srcS[j] : 0;
        float2 a2 = valid ? attn2[s] : make_float2(0.f, 0.f);
        float pm = valid ? __expf(fminf(lrelu(a2.x + amdv), 60.f)) : 0.f;
        float pl = valid ? __expf(fminf(lrelu(a2.y + aldv), 60.f)) : 0.f;
        int cnt = end - tb; if (cnt > 16) cnt = 16;
        for (int jj = 0; jj < cnt; jj += 2) {
            int idx = jj + e2;
            int sj    = __shfl(s, gb + idx, 64);
            float pmj = __shfl(pm, gb + idx, 64);
            float plj = __shfl(pl, gb + idx, 64);
            float w = isMu ? pmj : plj;
            if (idx >= cnt) w = 0.f;
            wsum += w;
            float4 hv = ldq_h16(hmhl16 + (size_t)sj * 32, q);
            acc.x += w * hv.x; acc.y += w * hv.y;
            acc.z += w * hv.z; acc.w += w * hv.w;
        }
    }
    wsum  += __shfl_xor(wsum, 8, 64);    // same q, other parity
    acc.x += __shfl_xor(acc.x, 8, 64);
    acc.y += __shfl_xor(acc.y, 8, 64);
    acc.z += __shfl_xor(acc.z, 8, 64);
    acc.w += __shfl_xor(acc.w, 8, 64);
    if (l < 8) {
        float inv = 1.f / wsum;          // s_m for q<4, s_l for q>=4
        if (q < 4) {
            float4 r;
            r.x = acc.x * inv + bm[4 * q + 0];
            r.y = acc.y * inv + bm[4 * q + 1];
            r.z = acc.z * inv + bm[4 * q + 2];
            r.w = acc.w * inv + bm[4 * q + 3];
            *(float4*)&out[(size_t)d * 16 + 4 * q] = r;
        } else {
            int qc = 4 * (q - 4);
            float4 r;
            r.x = acc.x * inv + bl[qc + 0];
            r.y = acc.y * inv + bl[qc + 1];
            r.z = acc.z * inv + bl[qc + 2];
            r.w = acc.w * inv + bl[qc + 3];
            *(float4*)&out[(size_t)n * 16 + (size_t)d * 16 + qc] = r;
        }
    }
}

extern "C" void kernel_launch(void* const* d_in, const int* in_sizes, int n_in,
                              void* d_out, int out_size, void* d_ws, size_t ws_size,
                              hipStream_t stream)
{
    const float* x   = (const float*)d_in[0];
    const int*   ei  = (const int*)d_in[1];
    const float* W1  = (const float*)d_in[2];
    const float* a1s = (const float*)d_in[3];
    const float* a1d = (const float*)d_in[4];
    const float* b1  = (const float*)d_in[5];
    const float* Wm  = (const float*)d_in[6];
    const float* ams = (const float*)d_in[7];
    const float* amd = (const float*)d_in[8];
    const float* bm  = (const float*)d_in[9];
    const float* Wl  = (const float*)d_in[10];
    const float* als = (const float*)d_in[11];
    const float* ald = (const float*)d_in[12];
    const float* bl  = (const float*)d_in[13];

    int n  = in_sizes[0] / 128;
    int E  = in_sizes[1] / 2;
    int Et = E + n;
    int wsz = (n + NW - 1) / NW;          // 391 for n=100000 (fits 9 bits, <=512)
    int cap = E / NW + 3072;              // 39-sigma slack
    const int* srcI = ei;
    const int* dstI = ei + E;

    float* ws = (float*)d_ws;
    // Layout (floats), peak ~ 71n + Et + 600 ≈ 35.5 MB:
    //  [0,16n)    h16 (fp16, n x 32 halves) — gemm1 out, l1 gather table
    //  [16n,32n)  hmhl16 (fp16, [mu16|ls16]) — gemm2 out, l2 gather table
    //  [32n,64n)  h1r fp32 (l1 out, gemm2 in), ALIASED with pairs (9.5MB) before l1
    //  [64n,66n)  as_,ad_  -> attn2 (float2) after l1
    //  [66n,67n)  amud ; [67n,68n) alsd
    //  [68n,69n)  deg | [69n,69n+NW) bcur | [70n,71n) rowS
    //  [71n,71n+Et) srcS
    u16*    h16   = (u16*)ws;
    u16*    hmhl16 = (u16*)(ws + (size_t)16 * n);
    float*  h1r  = ws + (size_t)32 * n;
    u32*    pairs = (u32*)(ws + (size_t)32 * n);
    float*  as_  = ws + (size_t)64 * n;
    float*  ad_  = ws + (size_t)65 * n;
    float2* attn2 = (float2*)(ws + (size_t)64 * n);
    float*  amud = ws + (size_t)66 * n;
    float*  alsd = ws + (size_t)67 * n;
    u32*    deg  = (u32*)(ws + (size_t)68 * n);
    u32*    bcur = (u32*)(ws + (size_t)69 * n);
    u32*    rowS = (u32*)(ws + (size_t)70 * n);
    int*    srcS = (int*)(ws + (size_t)71 * n);

    int pgrid = (E + PCHUNK - 1) / PCHUNK;
    int gblocks = (n + 63) / 64;

    hipMemsetAsync(bcur, 0, NW * sizeof(u32), stream);

    g1p_kernel<<<pgrid + gblocks, 256, 0, stream>>>(
        x, W1, a1s, a1d, h16, as_, ad_,
        srcI, dstI, pairs, bcur, n, E, wsz, cap, pgrid);

    csr_window_kernel<<<NW, 256, 0, stream>>>(pairs, bcur,
                                              rowS, deg, srcS, n, wsz, cap);

    l1_fused_kernel<<<(n + 15) / 16, 256, 0, stream>>>(rowS, deg, srcS, as_, ad_,
                                                       h16, b1, h1r, n);

    gemm2_kernel<<<(n + 15) / 16, 256, 0, stream>>>(h1r, Wm, Wl, ams, amd, als, ald,
                                                    hmhl16, attn2, amud, alsd, n);

    l2_fused_kernel<<<(n + 15) / 16, 256, 0, stream>>>(rowS, deg, srcS,
                                                       attn2, amud, alsd,
                                                       hmhl16, bm, bl,
                                                       (float*)d_out, n);
}